// Round 7
// baseline (550.646 us; speedup 1.0000x reference)
//
#include <hip/hip_runtime.h>

#define B_   2
#define D_   32
#define H_   256
#define W_   256
#define N_   150000
#define CIN  16
#define CMID 32
#define COUT 64
#define DO_  16
#define HO_  128
#define WO_  128
#define M_   (B_*DO_*HO_*WO_)   /* 524288 */
#define EPSf 1e-5f
#define NB_DOWN 8192             /* k_down blocks; %8==0, 64 voxels per block */
#define NREP 64                  /* stats slabs (atomic de-contention) */

// ---------------- grid scatter ----------------
__global__ __launch_bounds__(256) void k_scatter(const int* __restrict__ coords,
                                                 int* __restrict__ grid) {
    int i = blockIdx.x * 256 + threadIdx.x;
    if (i >= N_) return;
    const int4 c = *(const int4*)(coords + 4 * (size_t)i);
    grid[((c.x * D_ + c.y) * H_ + c.z) * W_ + c.w] = i;
}

// ---------------- weight transpose (27 real slots; slot 27 stays zero) ------
__global__ __launch_bounds__(256) void k_twist(const float* __restrict__ W1,
                                               const float* __restrict__ W2,
                                               const float* __restrict__ W3,
                                               float* __restrict__ Wt1,
                                               float* __restrict__ Wt2,
                                               float* __restrict__ Wt3) {
    const int t = blockIdx.x * 256 + threadIdx.x;
    if (t < 3456) {
        const int ki = t / 128, r = t % 128;
        const int co = r & 31, qh = r >> 5, hi = qh & 1, q = qh >> 1;
        const float* src = W1 + ki * 512 + (hi * 8 + q * 4) * 32 + co;
        float4 o; o.x = src[0]; o.y = src[32]; o.z = src[64]; o.w = src[96];
        ((float4*)Wt1)[t] = o;
    } else if (t < 3456 + 6912) {
        const int u = t - 3456;
        const int ki = u / 256, r = u % 256;
        const int co = r & 31, qh = r >> 5, hi = qh & 1, q = qh >> 1;
        const float* src = W2 + ki * 1024 + (hi * 16 + q * 4) * 32 + co;
        float4 o; o.x = src[0]; o.y = src[32]; o.z = src[64]; o.w = src[96];
        ((float4*)Wt2)[u] = o;
    } else if (t < 3456 + 6912 + 13824) {
        const int u = t - 3456 - 6912;
        const int ki = u / 512, r = u % 512;
        const int co = r & 63, q = r >> 6;
        const float* src = W3 + ki * 2048 + q * 4 * 64 + co;
        float4 o; o.x = src[0]; o.y = src[64]; o.z = src[128]; o.w = src[192];
        ((float4*)Wt3)[u] = o;
    }
}

// ---------------- submanifold conv: 4 points per wave, branch-free taps -----
// Dummy taps (ki=27 -> zero weights, ni=0) keep the loop body a single basic
// block: all 4 chains' loads issue together (deep MLP), one stall per iter.
template <int CI>
__global__ __launch_bounds__(256) void k_subm(const float* __restrict__ X,
                                              const int* __restrict__ coords,
                                              const int* __restrict__ grid,
                                              const float* __restrict__ Wt,
                                              const float* __restrict__ bias,
                                              float* __restrict__ Y,
                                              float* __restrict__ slab0) {
    const int wid  = (blockIdx.x * 256 + threadIdx.x) >> 6;
    const int lane = threadIdx.x & 63;
    const int sub  = lane & 31;
    const int half = lane >> 5;
    const int i0   = wid * 4;

    int nidx01 = -1, nidx23 = -1;
    {
        const int4 cc = *(const int4*)(coords + 4 * (size_t)(i0 + half));
        if (sub < 27) {
            const int nz = cc.y + sub / 9 - 1;
            const int ny = cc.z + (sub / 3) % 3 - 1;
            const int nx = cc.w + sub % 3 - 1;
            if ((unsigned)nz < (unsigned)D_ && (unsigned)ny < (unsigned)H_ &&
                (unsigned)nx < (unsigned)W_)
                nidx01 = grid[((cc.x * D_ + nz) * H_ + ny) * W_ + nx];
        }
    }
    {
        const int4 cc = *(const int4*)(coords + 4 * (size_t)(i0 + 2 + half));
        if (sub < 27) {
            const int nz = cc.y + sub / 9 - 1;
            const int ny = cc.z + (sub / 3) % 3 - 1;
            const int nx = cc.w + sub % 3 - 1;
            if ((unsigned)nz < (unsigned)D_ && (unsigned)ny < (unsigned)H_ &&
                (unsigned)nx < (unsigned)W_)
                nidx23 = grid[((cc.x * D_ + nz) * H_ + ny) * W_ + nx];
        }
    }
    const unsigned long long a01 = __ballot(nidx01 >= 0);
    const unsigned long long a23 = __ballot(nidx23 >= 0);
    unsigned m0 = (unsigned)a01 & 0x7FFFFFFu;
    unsigned m1 = (unsigned)(a01 >> 32) & 0x7FFFFFFu;
    unsigned m2 = (unsigned)a23 & 0x7FFFFFFu;
    unsigned m3 = (unsigned)(a23 >> 32) & 0x7FFFFFFu;

    float acc0 = 0.f, acc1 = 0.f, acc2 = 0.f, acc3 = 0.f;

    auto tap = [&](int ki, int nidx_src, int ofs, float& acc) {
        const int niv = __shfl(nidx_src, ki + ofs, 64);
        const int ni  = __builtin_amdgcn_readfirstlane(niv > 0 ? niv : 0);
        const float* __restrict__ fS = X + (size_t)ni * CI + half * (CI / 2);
        const float4* __restrict__ w4 =
            (const float4*)Wt + (size_t)ki * (CI * 8) + half * 32 + sub;
#pragma unroll
        for (int q = 0; q < CI / 8; ++q) {
            const float4 wv = w4[q * 64];
            acc = fmaf(fS[4 * q + 0], wv.x, acc);
            acc = fmaf(fS[4 * q + 1], wv.y, acc);
            acc = fmaf(fS[4 * q + 2], wv.z, acc);
            acc = fmaf(fS[4 * q + 3], wv.w, acc);
        }
    };

    while (m0 | m1 | m2 | m3) {
        const int ki0 = m0 ? __builtin_ctz(m0) : 27;  m0 &= m0 - 1;
        const int ki1 = m1 ? __builtin_ctz(m1) : 27;  m1 &= m1 - 1;
        const int ki2 = m2 ? __builtin_ctz(m2) : 27;  m2 &= m2 - 1;
        const int ki3 = m3 ? __builtin_ctz(m3) : 27;  m3 &= m3 - 1;
        tap(ki0, nidx01, 0,  acc0);
        tap(ki1, nidx01, 32, acc1);
        tap(ki2, nidx23, 0,  acc2);
        tap(ki3, nidx23, 32, acc3);
    }

    acc0 += __shfl_xor(acc0, 32, 64);
    acc1 += __shfl_xor(acc1, 32, 64);
    acc2 += __shfl_xor(acc2, 32, 64);
    acc3 += __shfl_xor(acc3, 32, 64);
    const float bv  = bias[sub];
    const float o01 = (half ? acc1 : acc0) + bv;
    const float o23 = (half ? acc3 : acc2) + bv;
    Y[(size_t)(i0 + half) * 32 + sub]     = o01;
    Y[(size_t)(i0 + 2 + half) * 32 + sub] = o23;

    // fused BN stats into NREP slabs (64 atomics per block over 64 slabs)
    __shared__ float sd[256];
    const int tid = threadIdx.x;
    float* __restrict__ slab = slab0 + (size_t)(blockIdx.x & (NREP - 1)) * 64;
    sd[tid] = o01 + o23;
    __syncthreads();
    if (tid < 32) {
        float t = 0.f;
#pragma unroll
        for (int k = 0; k < 8; ++k) t += sd[tid + 32 * k];
        atomicAdd(slab + tid, t);
    }
    __syncthreads();
    sd[tid] = o01 * o01 + o23 * o23;
    __syncthreads();
    if (tid < 32) {
        float t = 0.f;
#pragma unroll
        for (int k = 0; k < 8; ++k) t += sd[tid + 32 * k];
        atomicAdd(slab + 32 + tid, t);
    }
}

// ---------------- strided down conv: LDS grid rows + 4 branch-free chains ---
__global__ __launch_bounds__(256) void k_down(const float* __restrict__ X,
                                              const int* __restrict__ grid,
                                              const float* __restrict__ Wt3,
                                              const float* __restrict__ bias,
                                              float* __restrict__ Y,
                                              unsigned char* __restrict__ mask,
                                              float* __restrict__ slab0,
                                              int* __restrict__ nacts) {
    const int b    = blockIdx.x;
    const int swz  = (b & 7) * (NB_DOWN / 8) + (b >> 3);
    const int tid  = threadIdx.x;
    const int wv   = tid >> 6;
    const int lane = tid & 63;
    const int sub  = lane & 31;
    const int half = lane >> 5;

    const int vox0 = swz * 64;
    const int ox0  = vox0 & 127;      // 0 or 64
    int t = vox0 >> 7;
    const int oy = t & 127; t >>= 7;
    const int oz = t & 15;
    const int bb = t >> 4;

    __shared__ int   gl[9][132];
    __shared__ float sd[256];
    __shared__ int   scnt[4];

    const int gx0 = 2 * ox0 - 1;
    for (int e = tid; e < 9 * 132; e += 256) {
        const int r  = e / 132, xo = e % 132;
        const int z  = 2 * oz - 1 + r / 3;
        const int y  = 2 * oy - 1 + r % 3;
        const int x  = gx0 + xo;
        int v = -1;
        if ((unsigned)z < (unsigned)D_ && (unsigned)y < (unsigned)H_ &&
            (unsigned)x < (unsigned)W_ && xo < 129)
            v = grid[((bb * D_ + z) * H_ + y) * W_ + x];
        gl[r][xo] = v;
    }
    __syncthreads();

    const int dz = sub / 9, dy = (sub / 3) % 3, dx = sub % 3;
    const int row = (sub < 27) ? dz * 3 + dy : 0;

    const float bv = bias[lane];
    float s = 0.f, s2 = 0.f;
    int cnt = 0;

    auto tap = [&](int ki, int nidx_src, int ofs, float& acc) {
        const int niv = __shfl(nidx_src, ki + ofs, 64);
        const int ni  = __builtin_amdgcn_readfirstlane(niv > 0 ? niv : 0);
        const float* __restrict__ fS = X + (size_t)ni * CMID;
        const float4* __restrict__ w4 = (const float4*)Wt3 + (size_t)ki * 512 + lane;
#pragma unroll
        for (int q = 0; q < 8; ++q) {
            const float4 wv4 = w4[q * 64];
            acc = fmaf(fS[4 * q + 0], wv4.x, acc);
            acc = fmaf(fS[4 * q + 1], wv4.y, acc);
            acc = fmaf(fS[4 * q + 2], wv4.z, acc);
            acc = fmaf(fS[4 * q + 3], wv4.w, acc);
        }
    };

    for (int it = 0; it < 4; ++it) {
        const int v0 = wv * 16 + it * 4;   // local voxel base, 4 voxels/iter
        const int nA = (sub < 27) ? gl[row][2 * (v0 + half) + dx] : -1;
        const unsigned long long actA = __ballot(nA >= 0);
        const int nB = (sub < 27) ? gl[row][2 * (v0 + 2 + half) + dx] : -1;
        const unsigned long long actB = __ballot(nB >= 0);
        unsigned m0 = (unsigned)actA & 0x7FFFFFFu;
        unsigned m1 = (unsigned)(actA >> 32) & 0x7FFFFFFu;
        unsigned m2 = (unsigned)actB & 0x7FFFFFFu;
        unsigned m3 = (unsigned)(actB >> 32) & 0x7FFFFFFu;
        const int mk0 = m0 ? 1 : 0, mk1 = m1 ? 1 : 0;
        const int mk2 = m2 ? 1 : 0, mk3 = m3 ? 1 : 0;

        float a0 = 0.f, a1 = 0.f, a2 = 0.f, a3 = 0.f;
        while (m0 | m1 | m2 | m3) {
            const int ki0 = m0 ? __builtin_ctz(m0) : 27;  m0 &= m0 - 1;
            const int ki1 = m1 ? __builtin_ctz(m1) : 27;  m1 &= m1 - 1;
            const int ki2 = m2 ? __builtin_ctz(m2) : 27;  m2 &= m2 - 1;
            const int ki3 = m3 ? __builtin_ctz(m3) : 27;  m3 &= m3 - 1;
            tap(ki0, nA, 0,  a0);
            tap(ki1, nA, 32, a1);
            tap(ki2, nB, 0,  a2);
            tap(ki3, nB, 32, a3);
        }

        const int vg = vox0 + v0;
        const float o0 = mk0 ? a0 + bv : 0.f;
        const float o1 = mk1 ? a1 + bv : 0.f;
        const float o2 = mk2 ? a2 + bv : 0.f;
        const float o3 = mk3 ? a3 + bv : 0.f;
        Y[(size_t)vg * COUT + lane]       = o0;
        Y[(size_t)(vg + 1) * COUT + lane] = o1;
        Y[(size_t)(vg + 2) * COUT + lane] = o2;
        Y[(size_t)(vg + 3) * COUT + lane] = o3;
        if (lane == 0) {
            mask[vg]     = (unsigned char)mk0;
            mask[vg + 1] = (unsigned char)mk1;
            mask[vg + 2] = (unsigned char)mk2;
            mask[vg + 3] = (unsigned char)mk3;
            cnt += mk0 + mk1 + mk2 + mk3;
        }
        s  += o0 + o1 + o2 + o3;
        s2 += o0 * o0 + o1 * o1 + o2 * o2 + o3 * o3;
    }

    float* __restrict__ slab = slab0 + (size_t)(b & (NREP - 1)) * 128;
    sd[tid] = s;
    if (lane == 0) scnt[wv] = cnt;
    __syncthreads();
    if (tid < 64) atomicAdd(slab + tid, sd[tid] + sd[tid + 64] + sd[tid + 128] + sd[tid + 192]);
    __syncthreads();
    sd[tid] = s2;
    __syncthreads();
    if (tid < 64) atomicAdd(slab + 64 + tid, sd[tid] + sd[tid + 64] + sd[tid + 128] + sd[tid + 192]);
    if (tid == 0) atomicAdd(nacts + (b & (NREP - 1)), scnt[0] + scnt[1] + scnt[2] + scnt[3]);
}

// ---------------- finalize scale/shift from NREP slabs (stages 1,2) ---------
template <int C>
__global__ void k_finslab(const float* __restrict__ slab0,
                          const float* __restrict__ g,
                          const float* __restrict__ be,
                          float n, float* __restrict__ ss) {
    const int c = threadIdx.x;
    if (c >= C) return;
    float sm = 0.f, s2 = 0.f;
    for (int r = 0; r < NREP; ++r) {
        sm += slab0[r * 2 * C + c];
        s2 += slab0[r * 2 * C + C + c];
    }
    const float m  = sm / n;
    const float v  = s2 / n - m * m;
    const float sc = g[c] * rsqrtf(v + EPSf);
    ss[c]     = sc;
    ss[C + c] = be[c] - m * sc;
}

// ---------------- finalize scale/shift (stage 3, folds NREP replicas) -------
__global__ void k_finstats3(const float* __restrict__ slab0,
                            const int* __restrict__ nacts,
                            const float* __restrict__ g,
                            const float* __restrict__ be,
                            float* __restrict__ ss) {
    const int c = threadIdx.x;   // 64 threads
    if (c >= 64) return;
    float sm = 0.f, s2 = 0.f;
    int na = 0;
    for (int r = 0; r < NREP; ++r) {
        sm += slab0[r * 128 + c];
        s2 += slab0[r * 128 + 64 + c];
        na += nacts[r];
    }
    const float n  = (float)(na > 0 ? na : 1);
    const float m  = sm / n;
    const float v  = s2 / n - m * m;
    const float sc = g[c] * rsqrtf(v + EPSf);
    ss[c]      = sc;
    ss[64 + c] = be[c] - m * sc;
}

// ---------------- normalize (BN+ReLU) ----------------
template <int C>
__global__ __launch_bounds__(256) void k_norm(const float* __restrict__ Y,
                                              const float* __restrict__ ss,
                                              float* __restrict__ Xo, long n4) {
    const long t = (long)blockIdx.x * 256 + threadIdx.x;
    if (t >= n4) return;
    const float4 y = ((const float4*)Y)[t];
    const int ch = (int)((t * 4) % C);
    float4 o;
    o.x = fmaxf(fmaf(y.x, ss[ch],     ss[C + ch]),     0.f);
    o.y = fmaxf(fmaf(y.y, ss[ch + 1], ss[C + ch + 1]), 0.f);
    o.z = fmaxf(fmaf(y.z, ss[ch + 2], ss[C + ch + 2]), 0.f);
    o.w = fmaxf(fmaf(y.w, ss[ch + 3], ss[C + ch + 3]), 0.f);
    ((float4*)Xo)[t] = o;
}

__global__ __launch_bounds__(256) void k_norm3(float* __restrict__ Y,
                                               const unsigned char* __restrict__ mask,
                                               const float* __restrict__ ss) {
    const long n4 = (long)M_ * COUT / 4;
    const long t = (long)blockIdx.x * 256 + threadIdx.x;
    if (t >= n4) return;
    const long vox = t >> 4;
    const float4 y = ((const float4*)Y)[t];
    const int ch = (int)((t * 4) & 63);
    float4 o;
    if (mask[vox]) {
        o.x = fmaxf(fmaf(y.x, ss[ch],     ss[64 + ch]),     0.f);
        o.y = fmaxf(fmaf(y.y, ss[ch + 1], ss[64 + ch + 1]), 0.f);
        o.z = fmaxf(fmaf(y.z, ss[ch + 2], ss[64 + ch + 2]), 0.f);
        o.w = fmaxf(fmaf(y.w, ss[ch + 3], ss[64 + ch + 3]), 0.f);
    } else {
        o.x = o.y = o.z = o.w = 0.f;
    }
    ((float4*)Y)[t] = o;
}

extern "C" void kernel_launch(void* const* d_in, const int* in_sizes, int n_in,
                              void* d_out, int out_size, void* d_ws, size_t ws_size,
                              hipStream_t stream) {
    const float* feats = (const float*)d_in[0];
    const int*   coords = (const int*)d_in[1];
    const float* W1 = (const float*)d_in[2];
    const float* b1 = (const float*)d_in[3];
    const float* g1 = (const float*)d_in[4];
    const float* be1 = (const float*)d_in[5];
    const float* W2 = (const float*)d_in[6];
    const float* b2 = (const float*)d_in[7];
    const float* g2 = (const float*)d_in[8];
    const float* be2 = (const float*)d_in[9];
    const float* W3 = (const float*)d_in[10];
    const float* b3 = (const float*)d_in[11];
    const float* g3 = (const float*)d_in[12];
    const float* be3 = (const float*)d_in[13];
    float* out = (float*)d_out;

    char* ws = (char*)d_ws;
    const size_t gridBytes = (size_t)B_ * D_ * H_ * W_ * 4;   // 16,777,216
    const size_t bufBytes  = (size_t)N_ * CMID * 4;           // 19,200,000
    int*   grid = (int*)ws;
    float* bufA = (float*)(ws + gridBytes);
    float* bufB = (float*)(ws + gridBytes + bufBytes);
    unsigned char* mask = (unsigned char*)(ws + gridBytes + 2 * bufBytes);
    float* stats = (float*)(ws + gridBytes + 2 * bufBytes + (size_t)M_);

    float* ss1   = stats + 260;
    float* ss2   = stats + 324;
    float* ss3   = stats + 388;
    float* slab1 = stats + 1024;              // NREP x 64 floats
    float* slab2 = stats + 1024 + 4096;       // NREP x 64 floats
    float* slab3 = stats + 1024 + 8192;       // NREP x 128 floats
    int*   nacts = (int*)(stats + 1024 + 16384);   // NREP ints
    float* Wt1 = stats + 20480;               // 28*512  floats (slot 27 = zeros)
    float* Wt2 = Wt1 + 28 * 512;              // 28*1024 floats
    float* Wt3 = Wt2 + 28 * 1024;             // 28*2048 floats

    hipMemsetAsync(grid, 0xFF, gridBytes, stream);
    hipMemsetAsync(stats + 1024, 0, (16384 + 64) * 4, stream);
    hipMemsetAsync(Wt1 + 27 * 512,  0, 512 * 4,  stream);
    hipMemsetAsync(Wt2 + 27 * 1024, 0, 1024 * 4, stream);
    hipMemsetAsync(Wt3 + 27 * 2048, 0, 2048 * 4, stream);

    k_scatter<<<(N_ + 255) / 256, 256, 0, stream>>>(coords, grid);
    k_twist<<<(24192 + 255) / 256, 256, 0, stream>>>(W1, W2, W3, Wt1, Wt2, Wt3);

    const int nb_subm = N_ / 16;   // 9375 blocks: 4 waves x 4 points
    k_subm<CIN><<<nb_subm, 256, 0, stream>>>(feats, coords, grid, Wt1, b1, bufA, slab1);
    k_finslab<CMID><<<1, 64, 0, stream>>>(slab1, g1, be1, (float)N_, ss1);
    k_norm<CMID><<<(N_ * CMID / 4 + 255) / 256, 256, 0, stream>>>(bufA, ss1, bufB,
                                                                  (long)N_ * CMID / 4);

    k_subm<CMID><<<nb_subm, 256, 0, stream>>>(bufB, coords, grid, Wt2, b2, bufA, slab2);
    k_finslab<CMID><<<1, 64, 0, stream>>>(slab2, g2, be2, (float)N_, ss2);
    k_norm<CMID><<<(N_ * CMID / 4 + 255) / 256, 256, 0, stream>>>(bufA, ss2, bufB,
                                                                  (long)N_ * CMID / 4);

    k_down<<<NB_DOWN, 256, 0, stream>>>(bufB, grid, Wt3, b3, out, mask, slab3, nacts);
    k_finstats3<<<1, 64, 0, stream>>>(slab3, nacts, g3, be3, ss3);
    k_norm3<<<(M_ * COUT / 4) / 256, 256, 0, stream>>>(out, mask, ss3);
}

// Round 8
// 309.355 us; speedup vs baseline: 1.7800x; 1.7800x over previous
//
#include <hip/hip_runtime.h>

#define B_   2
#define D_   32
#define H_   256
#define W_   256
#define N_   150000
#define CIN  16
#define CMID 32
#define COUT 64
#define DO_  16
#define HO_  128
#define WO_  128
#define M_   (B_*DO_*HO_*WO_)   /* 524288 */
#define EPSf 1e-5f
#define NB_DOWN 8192             /* k_down blocks; %8==0, 64 voxels per block */
#define NREP 64                  /* stage-3 stats slabs (atomic de-contention) */

// bf16-pair unpack: lo = even-ci weight, hi = odd-ci weight
__device__ inline float lo16(unsigned u) { return __uint_as_float(u << 16); }
__device__ inline float hi16(unsigned u) { return __uint_as_float(u & 0xFFFF0000u); }
// RNE pack of two floats into one dword of bf16s (a -> lo, b -> hi)
__device__ inline unsigned bfp(float a, float b) {
    unsigned ua = __float_as_uint(a), ub = __float_as_uint(b);
    ua = (ua + 0x7FFFu + ((ua >> 16) & 1u)) >> 16;
    ub = (ub + 0x7FFFu + ((ub >> 16) & 1u)) & 0xFFFF0000u;
    return ua | ub;
}

// ---------------- grid scatter ----------------
__global__ __launch_bounds__(256) void k_scatter(const int* __restrict__ coords,
                                                 int* __restrict__ grid) {
    int i = blockIdx.x * 256 + threadIdx.x;
    if (i >= N_) return;
    const int4 c = *(const int4*)(coords + 4 * (size_t)i);
    grid[((c.x * D_ + c.y) * H_ + c.z) * W_ + c.w] = i;
}

// ---------------- weight transpose+pack to bf16 pairs ----------------
// Wb1: uint4 at (ki*2+half)*32+sub              (CI=16: 8 w / lane / tap)
// Wb2: uint4 at ((ki*2+half)*2+q)*32+sub, q<2   (CI=32: 16 w / lane / tap)
// Wb3: uint4 at (ki*4+q)*64+lane, q<4           (32 w / lane / tap)
__global__ __launch_bounds__(256) void k_twist(const float* __restrict__ W1,
                                               const float* __restrict__ W2,
                                               const float* __restrict__ W3,
                                               uint4* __restrict__ Wb1,
                                               uint4* __restrict__ Wb2,
                                               uint4* __restrict__ Wb3) {
    const int t = blockIdx.x * 256 + threadIdx.x;
    if (t < 1728) {
        const int ki = t / 64, r = t % 64, half = r >> 5, sub = r & 31;
        const float* base = W1 + ki * 512 + (half * 8) * 32 + sub;
        uint4 o;
        o.x = bfp(base[0],   base[32]);
        o.y = bfp(base[64],  base[96]);
        o.z = bfp(base[128], base[160]);
        o.w = bfp(base[192], base[224]);
        Wb1[(ki * 2 + half) * 32 + sub] = o;
    } else if (t < 1728 + 3456) {
        const int u = t - 1728;
        const int ki = u / 128, r = u % 128, qh = r >> 5, sub = r & 31;
        const int half = qh >> 1, q = qh & 1;
        const float* base = W2 + ki * 1024 + (half * 16 + q * 8) * 32 + sub;
        uint4 o;
        o.x = bfp(base[0],   base[32]);
        o.y = bfp(base[64],  base[96]);
        o.z = bfp(base[128], base[160]);
        o.w = bfp(base[192], base[224]);
        Wb2[((ki * 2 + half) * 2 + q) * 32 + sub] = o;
    } else if (t < 1728 + 3456 + 6912) {
        const int u = t - 5184;
        const int ki = u / 256, r = u % 256, q = r >> 6, lane = r & 63;
        const float* base = W3 + ki * 2048 + (q * 8) * 64 + lane;
        uint4 o;
        o.x = bfp(base[0],   base[64]);
        o.y = bfp(base[128], base[192]);
        o.z = bfp(base[256], base[320]);
        o.w = bfp(base[384], base[448]);
        Wb3[(ki * 4 + q) * 64 + lane] = o;
    }
}

// ---------------- submanifold conv: one wave per POINT-PAIR ----------------
template <int CI>
__global__ __launch_bounds__(256) void k_subm(const float* __restrict__ X,
                                              const int* __restrict__ coords,
                                              const int* __restrict__ grid,
                                              const uint4* __restrict__ Wb,
                                              const float* __restrict__ bias,
                                              float* __restrict__ Y) {
    constexpr int NQ = CI / 16;   // uint4 weight loads per tap per lane
    const int pid  = (blockIdx.x * 256 + threadIdx.x) >> 6;
    const int lane = threadIdx.x & 63;
    const int sub  = lane & 31;
    const int half = lane >> 5;
    const int iA   = pid * 2;

    const int4 cA = *(const int4*)(coords + 4 * (size_t)iA);
    const int4 cB = *(const int4*)(coords + 4 * (size_t)(iA + 1));
    const int4 cc = half ? cB : cA;

    int nidx = -1;
    if (sub < 27) {
        const int nz = cc.y + sub / 9 - 1;
        const int ny = cc.z + (sub / 3) % 3 - 1;
        const int nx = cc.w + sub % 3 - 1;
        if ((unsigned)nz < (unsigned)D_ && (unsigned)ny < (unsigned)H_ &&
            (unsigned)nx < (unsigned)W_)
            nidx = grid[((cc.x * D_ + nz) * H_ + ny) * W_ + nx];
    }
    const unsigned long long act = __ballot(nidx >= 0);
    unsigned int actA = (unsigned int)(act & 0x7FFFFFFull);
    unsigned int actB = (unsigned int)((act >> 32) & 0x7FFFFFFull);

    float accA = 0.f, accB = 0.f;

    while (actA | actB) {
        if (actA) {
            const int ki = __builtin_ctz(actA); actA &= actA - 1;
            const int ni = __shfl(nidx, ki, 64);
            const float* __restrict__ f = X + (size_t)ni * CI + half * (CI / 2);
            const uint4* __restrict__ wb = Wb + ((size_t)(ki * 2 + half)) * NQ * 32 + sub;
#pragma unroll
            for (int q = 0; q < NQ; ++q) {
                const uint4 wu = wb[q * 32];
                const float4 fa = *(const float4*)(f + q * 8);
                const float4 fb = *(const float4*)(f + q * 8 + 4);
                accA = fmaf(fa.x, lo16(wu.x), accA);
                accA = fmaf(fa.y, hi16(wu.x), accA);
                accA = fmaf(fa.z, lo16(wu.y), accA);
                accA = fmaf(fa.w, hi16(wu.y), accA);
                accA = fmaf(fb.x, lo16(wu.z), accA);
                accA = fmaf(fb.y, hi16(wu.z), accA);
                accA = fmaf(fb.z, lo16(wu.w), accA);
                accA = fmaf(fb.w, hi16(wu.w), accA);
            }
        }
        if (actB) {
            const int ki = __builtin_ctz(actB); actB &= actB - 1;
            const int ni = __shfl(nidx, ki + 32, 64);
            const float* __restrict__ f = X + (size_t)ni * CI + half * (CI / 2);
            const uint4* __restrict__ wb = Wb + ((size_t)(ki * 2 + half)) * NQ * 32 + sub;
#pragma unroll
            for (int q = 0; q < NQ; ++q) {
                const uint4 wu = wb[q * 32];
                const float4 fa = *(const float4*)(f + q * 8);
                const float4 fb = *(const float4*)(f + q * 8 + 4);
                accB = fmaf(fa.x, lo16(wu.x), accB);
                accB = fmaf(fa.y, hi16(wu.x), accB);
                accB = fmaf(fa.z, lo16(wu.y), accB);
                accB = fmaf(fa.w, hi16(wu.y), accB);
                accB = fmaf(fb.x, lo16(wu.z), accB);
                accB = fmaf(fb.y, hi16(wu.z), accB);
                accB = fmaf(fb.z, lo16(wu.w), accB);
                accB = fmaf(fb.w, hi16(wu.w), accB);
            }
        }
    }

    accA += __shfl_xor(accA, 32, 64);     // combine ci halves
    accB += __shfl_xor(accB, 32, 64);
    const float outv = (half ? accB : accA) + bias[sub];
    Y[(size_t)(iA + half) * 32 + sub] = outv;
}

// ---------------- strided down conv: LDS-staged grid rows -------------------
__global__ __launch_bounds__(256) void k_down(const float* __restrict__ X,
                                              const int* __restrict__ grid,
                                              const uint4* __restrict__ Wb3,
                                              const float* __restrict__ bias,
                                              float* __restrict__ Y,
                                              unsigned char* __restrict__ mask,
                                              float* __restrict__ slab0,
                                              int* __restrict__ nacts) {
    const int b    = blockIdx.x;
    const int swz  = (b & 7) * (NB_DOWN / 8) + (b >> 3);
    const int tid  = threadIdx.x;
    const int wv   = tid >> 6;
    const int lane = tid & 63;
    const int sub  = lane & 31;
    const int half = lane >> 5;

    const int vox0 = swz * 64;
    const int ox0  = vox0 & 127;      // 0 or 64
    int t = vox0 >> 7;
    const int oy = t & 127; t >>= 7;
    const int oz = t & 15;
    const int bb = t >> 4;

    __shared__ int   gl[9][132];
    __shared__ float sd[256];
    __shared__ int   scnt[4];

    const int gx0 = 2 * ox0 - 1;
    for (int e = tid; e < 9 * 132; e += 256) {
        const int r  = e / 132, xo = e % 132;
        const int z  = 2 * oz - 1 + r / 3;
        const int y  = 2 * oy - 1 + r % 3;
        const int x  = gx0 + xo;
        int v = -1;
        if ((unsigned)z < (unsigned)D_ && (unsigned)y < (unsigned)H_ &&
            (unsigned)x < (unsigned)W_ && xo < 129)
            v = grid[((bb * D_ + z) * H_ + y) * W_ + x];
        gl[r][xo] = v;
    }
    __syncthreads();

    const int dz = sub / 9, dy = (sub / 3) % 3, dx = sub % 3;
    const int row = (sub < 27) ? dz * 3 + dy : 0;

    const float bv = bias[lane];
    float s = 0.f, s2 = 0.f;
    int cnt = 0;

    for (int it = 0; it < 8; ++it) {
        const int pr = wv * 8 + it;                 // pair index 0..31
        const int xo = 2 * (pr * 2 + half) + dx;    // 0..128
        const int nidx = (sub < 27) ? gl[row][xo] : -1;

        const unsigned long long act = __ballot(nidx >= 0);
        unsigned int actA = (unsigned int)(act & 0x7FFFFFFull);
        unsigned int actB = (unsigned int)((act >> 32) & 0x7FFFFFFull);
        const int mkA = actA ? 1 : 0;
        const int mkB = actB ? 1 : 0;

        float accA = 0.f, accB = 0.f;
        while (actA | actB) {
            if (actA) {
                const int ki = __builtin_ctz(actA); actA &= actA - 1;
                const int ni = __builtin_amdgcn_readfirstlane(__shfl(nidx, ki, 64));
                const float* __restrict__ fS = X + (size_t)ni * CMID;   // SGPR base
                const uint4* __restrict__ wb = Wb3 + (size_t)ki * 256 + lane;
#pragma unroll
                for (int q = 0; q < 4; ++q) {
                    const uint4 wu = wb[q * 64];
                    accA = fmaf(fS[8 * q + 0], lo16(wu.x), accA);
                    accA = fmaf(fS[8 * q + 1], hi16(wu.x), accA);
                    accA = fmaf(fS[8 * q + 2], lo16(wu.y), accA);
                    accA = fmaf(fS[8 * q + 3], hi16(wu.y), accA);
                    accA = fmaf(fS[8 * q + 4], lo16(wu.z), accA);
                    accA = fmaf(fS[8 * q + 5], hi16(wu.z), accA);
                    accA = fmaf(fS[8 * q + 6], lo16(wu.w), accA);
                    accA = fmaf(fS[8 * q + 7], hi16(wu.w), accA);
                }
            }
            if (actB) {
                const int ki = __builtin_ctz(actB); actB &= actB - 1;
                const int ni = __builtin_amdgcn_readfirstlane(__shfl(nidx, ki + 32, 64));
                const float* __restrict__ fS = X + (size_t)ni * CMID;
                const uint4* __restrict__ wb = Wb3 + (size_t)ki * 256 + lane;
#pragma unroll
                for (int q = 0; q < 4; ++q) {
                    const uint4 wu = wb[q * 64];
                    accB = fmaf(fS[8 * q + 0], lo16(wu.x), accB);
                    accB = fmaf(fS[8 * q + 1], hi16(wu.x), accB);
                    accB = fmaf(fS[8 * q + 2], lo16(wu.y), accB);
                    accB = fmaf(fS[8 * q + 3], hi16(wu.y), accB);
                    accB = fmaf(fS[8 * q + 4], lo16(wu.z), accB);
                    accB = fmaf(fS[8 * q + 5], hi16(wu.z), accB);
                    accB = fmaf(fS[8 * q + 6], lo16(wu.w), accB);
                    accB = fmaf(fS[8 * q + 7], hi16(wu.w), accB);
                }
            }
        }

        const int vA = vox0 + pr * 2;
        const float oA = mkA ? accA + bv : 0.f;
        const float oB = mkB ? accB + bv : 0.f;
        Y[(size_t)vA * COUT + lane]       = oA;
        Y[(size_t)(vA + 1) * COUT + lane] = oB;
        if (lane == 0) {
            mask[vA]     = (unsigned char)mkA;
            mask[vA + 1] = (unsigned char)mkB;
            cnt += mkA + mkB;
        }
        s  += oA + oB;
        s2 += oA * oA + oB * oB;
    }

    float* __restrict__ slab = slab0 + (size_t)(b & (NREP - 1)) * 128;
    sd[tid] = s;
    if (lane == 0) scnt[wv] = cnt;
    __syncthreads();
    if (tid < 64) atomicAdd(slab + tid, sd[tid] + sd[tid + 64] + sd[tid + 128] + sd[tid + 192]);
    __syncthreads();
    sd[tid] = s2;
    __syncthreads();
    if (tid < 64) atomicAdd(slab + 64 + tid, sd[tid] + sd[tid + 64] + sd[tid + 128] + sd[tid + 192]);
    if (tid == 0) atomicAdd(nacts + (b & (NREP - 1)), scnt[0] + scnt[1] + scnt[2] + scnt[3]);
}

// ---------------- per-channel sum / sumsq (stages 1,2) ----------------
template <int C>
__global__ __launch_bounds__(256) void k_stats(const float* __restrict__ Y,
                                               long n_elems,
                                               float* __restrict__ stats) {
    __shared__ float sdata[256];
    const int t = threadIdx.x;
    const long stride = (long)gridDim.x * 256;
    float s = 0.f, s2 = 0.f;
    for (long idx = (long)blockIdx.x * 256 + t; idx < n_elems; idx += stride) {
        const float v = Y[idx];
        s += v; s2 += v * v;
    }
    sdata[t] = s; __syncthreads();
    for (int off = 128; off >= C; off >>= 1) {
        if (t < off) sdata[t] += sdata[t + off];
        __syncthreads();
    }
    if (t < C) atomicAdd(stats + t, sdata[t]);
    __syncthreads();
    sdata[t] = s2; __syncthreads();
    for (int off = 128; off >= C; off >>= 1) {
        if (t < off) sdata[t] += sdata[t + off];
        __syncthreads();
    }
    if (t < C) atomicAdd(stats + C + t, sdata[t]);
}

// ---------------- finalize scale/shift (stages 1,2) ----------------
template <int C>
__global__ void k_finstats(const float* __restrict__ stats,
                           const float* __restrict__ g,
                           const float* __restrict__ be,
                           float nfix,
                           float* __restrict__ ss) {
    const int c = threadIdx.x;
    if (c >= C) return;
    const float n  = nfix;
    const float m  = stats[c] / n;
    const float v  = stats[C + c] / n - m * m;
    const float sc = g[c] * rsqrtf(v + EPSf);
    ss[c]     = sc;
    ss[C + c] = be[c] - m * sc;
}

// ---------------- finalize scale/shift (stage 3, folds NREP replicas) -------
__global__ void k_finstats3(const float* __restrict__ slab0,
                            const int* __restrict__ nacts,
                            const float* __restrict__ g,
                            const float* __restrict__ be,
                            float* __restrict__ ss) {
    const int c = threadIdx.x;   // 64 threads
    if (c >= 64) return;
    float sm = 0.f, s2 = 0.f;
    int na = 0;
    for (int r = 0; r < NREP; ++r) {
        sm += slab0[r * 128 + c];
        s2 += slab0[r * 128 + 64 + c];
        na += nacts[r];
    }
    const float n  = (float)(na > 0 ? na : 1);
    const float m  = sm / n;
    const float v  = s2 / n - m * m;
    const float sc = g[c] * rsqrtf(v + EPSf);
    ss[c]      = sc;
    ss[64 + c] = be[c] - m * sc;
}

// ---------------- normalize (BN+ReLU) ----------------
template <int C>
__global__ __launch_bounds__(256) void k_norm(const float* __restrict__ Y,
                                              const float* __restrict__ ss,
                                              float* __restrict__ Xo, long n4) {
    const long t = (long)blockIdx.x * 256 + threadIdx.x;
    if (t >= n4) return;
    const float4 y = ((const float4*)Y)[t];
    const int ch = (int)((t * 4) % C);
    float4 o;
    o.x = fmaxf(fmaf(y.x, ss[ch],     ss[C + ch]),     0.f);
    o.y = fmaxf(fmaf(y.y, ss[ch + 1], ss[C + ch + 1]), 0.f);
    o.z = fmaxf(fmaf(y.z, ss[ch + 2], ss[C + ch + 2]), 0.f);
    o.w = fmaxf(fmaf(y.w, ss[ch + 3], ss[C + ch + 3]), 0.f);
    ((float4*)Xo)[t] = o;
}

__global__ __launch_bounds__(256) void k_norm3(float* __restrict__ Y,
                                               const unsigned char* __restrict__ mask,
                                               const float* __restrict__ ss) {
    const long n4 = (long)M_ * COUT / 4;
    const long t = (long)blockIdx.x * 256 + threadIdx.x;
    if (t >= n4) return;
    const long vox = t >> 4;
    const float4 y = ((const float4*)Y)[t];
    const int ch = (int)((t * 4) & 63);
    float4 o;
    if (mask[vox]) {
        o.x = fmaxf(fmaf(y.x, ss[ch],     ss[64 + ch]),     0.f);
        o.y = fmaxf(fmaf(y.y, ss[ch + 1], ss[64 + ch + 1]), 0.f);
        o.z = fmaxf(fmaf(y.z, ss[ch + 2], ss[64 + ch + 2]), 0.f);
        o.w = fmaxf(fmaf(y.w, ss[ch + 3], ss[64 + ch + 3]), 0.f);
    } else {
        o.x = o.y = o.z = o.w = 0.f;
    }
    ((float4*)Y)[t] = o;
}

extern "C" void kernel_launch(void* const* d_in, const int* in_sizes, int n_in,
                              void* d_out, int out_size, void* d_ws, size_t ws_size,
                              hipStream_t stream) {
    const float* feats = (const float*)d_in[0];
    const int*   coords = (const int*)d_in[1];
    const float* W1 = (const float*)d_in[2];
    const float* b1 = (const float*)d_in[3];
    const float* g1 = (const float*)d_in[4];
    const float* be1 = (const float*)d_in[5];
    const float* W2 = (const float*)d_in[6];
    const float* b2 = (const float*)d_in[7];
    const float* g2 = (const float*)d_in[8];
    const float* be2 = (const float*)d_in[9];
    const float* W3 = (const float*)d_in[10];
    const float* b3 = (const float*)d_in[11];
    const float* g3 = (const float*)d_in[12];
    const float* be3 = (const float*)d_in[13];
    float* out = (float*)d_out;

    char* ws = (char*)d_ws;
    const size_t gridBytes = (size_t)B_ * D_ * H_ * W_ * 4;   // 16,777,216
    const size_t bufBytes  = (size_t)N_ * CMID * 4;           // 19,200,000
    int*   grid = (int*)ws;
    float* bufA = (float*)(ws + gridBytes);
    float* bufB = (float*)(ws + gridBytes + bufBytes);
    unsigned char* mask = (unsigned char*)(ws + gridBytes + 2 * bufBytes);
    float* stats = (float*)(ws + gridBytes + 2 * bufBytes + (size_t)M_);

    float* st1   = stats;                 // 32 sum + 32 sumsq
    float* st2   = stats + 64;            // 32 sum + 32 sumsq
    float* ss1   = stats + 260;
    float* ss2   = stats + 324;
    float* ss3   = stats + 388;
    float* slab3 = stats + 1024;          // NREP x 128 floats
    int*   nacts = (int*)(stats + 1024 + NREP * 128);   // NREP ints
    uint4* Wb1 = (uint4*)(stats + 16384);               // 1728 uint4
    uint4* Wb2 = Wb1 + 1728;                            // 3456 uint4
    uint4* Wb3 = Wb2 + 3456;                            // 6912 uint4

    hipMemsetAsync(grid, 0xFF, gridBytes, stream);
    hipMemsetAsync(stats, 0, 256 * 4, stream);                       // st1,st2
    hipMemsetAsync(stats + 1024, 0, (NREP * 128 + NREP) * 4, stream); // slab3+nacts

    k_scatter<<<(N_ + 255) / 256, 256, 0, stream>>>(coords, grid);
    k_twist<<<(12096 + 255) / 256, 256, 0, stream>>>(W1, W2, W3, Wb1, Wb2, Wb3);

    const int nb_subm = 75000 / 4;   // 18750, exact (pairs, 4 waves/block)
    k_subm<CIN><<<nb_subm, 256, 0, stream>>>(feats, coords, grid, Wb1, b1, bufA);
    k_stats<CMID><<<512, 256, 0, stream>>>(bufA, (long)N_ * CMID, st1);
    k_finstats<CMID><<<1, 64, 0, stream>>>(st1, g1, be1, (float)N_, ss1);
    k_norm<CMID><<<(N_ * CMID / 4 + 255) / 256, 256, 0, stream>>>(bufA, ss1, bufB,
                                                                  (long)N_ * CMID / 4);

    k_subm<CMID><<<nb_subm, 256, 0, stream>>>(bufB, coords, grid, Wb2, b2, bufA);
    k_stats<CMID><<<512, 256, 0, stream>>>(bufA, (long)N_ * CMID, st2);
    k_finstats<CMID><<<1, 64, 0, stream>>>(st2, g2, be2, (float)N_, ss2);
    k_norm<CMID><<<(N_ * CMID / 4 + 255) / 256, 256, 0, stream>>>(bufA, ss2, bufB,
                                                                  (long)N_ * CMID / 4);

    k_down<<<NB_DOWN, 256, 0, stream>>>(bufB, grid, Wb3, b3, out, mask, slab3, nacts);
    k_finstats3<<<1, 64, 0, stream>>>(slab3, nacts, g3, be3, ss3);
    k_norm3<<<(M_ * COUT / 4) / 256, 256, 0, stream>>>(out, mask, ss3);
}

// Round 9
// 288.727 us; speedup vs baseline: 1.9072x; 1.0714x over previous
//
#include <hip/hip_runtime.h>

#define B_   2
#define D_   32
#define H_   256
#define W_   256
#define N_   150000
#define CIN  16
#define CMID 32
#define COUT 64
#define DO_  16
#define HO_  128
#define WO_  128
#define M_   (B_*DO_*HO_*WO_)   /* 524288 */
#define EPSf 1e-5f
#define NB_DOWN 8192             /* k_down blocks; %8==0, 64 voxels per block */
#define NREP 64                  /* stage-3 stats slabs (atomic de-contention) */

typedef _Float16 h2 __attribute__((ext_vector_type(2)));
__device__ inline h2 as_h2(unsigned u) { union { unsigned u; h2 h; } x; x.u = u; return x.h; }

#if defined(__has_builtin) && __has_builtin(__builtin_amdgcn_fdot2)
__device__ inline float dot2(unsigned f, unsigned w, float acc) {
    return __builtin_amdgcn_fdot2(as_h2(f), as_h2(w), acc, false);
}
#else
__device__ inline float dot2(unsigned f, unsigned w, float acc) {
    const h2 a = as_h2(f), b = as_h2(w);
    return fmaf((float)a.x, (float)b.x, fmaf((float)a.y, (float)b.y, acc));
}
#endif

// pack two floats into one dword of fp16 (RNE via _Float16 cast)
__device__ inline unsigned hpk(float a, float b) {
    union { _Float16 h[2]; unsigned u; } x;
    x.h[0] = (_Float16)a; x.h[1] = (_Float16)b; return x.u;
}

// ---------------- grid scatter ----------------
__global__ __launch_bounds__(256) void k_scatter(const int* __restrict__ coords,
                                                 int* __restrict__ grid) {
    int i = blockIdx.x * 256 + threadIdx.x;
    if (i >= N_) return;
    const int4 c = *(const int4*)(coords + 4 * (size_t)i);
    grid[((c.x * D_ + c.y) * H_ + c.z) * W_ + c.w] = i;
}

// ---------------- weight transpose+pack to fp16 pairs ----------------
// Wh1: uint4 at (ki*2+half)*32+sub           dword j = (ci=h*8+2j, +1)
// Wh2: uint4 at ((ki*2+half)*2+q)*32+sub     dword j = (ci=h*16+q*8+2j, +1)
// Wh3: uint4 at (ki*4+q)*64+lane             dword j = (ci=q*8+2j, +1), co=lane
__global__ __launch_bounds__(256) void k_twisth(const float* __restrict__ W1,
                                                const float* __restrict__ W2,
                                                const float* __restrict__ W3,
                                                uint4* __restrict__ Wh1,
                                                uint4* __restrict__ Wh2,
                                                uint4* __restrict__ Wh3) {
    const int t = blockIdx.x * 256 + threadIdx.x;
    if (t < 1728) {
        const int ki = t / 64, r = t % 64, half = r >> 5, sub = r & 31;
        const float* base = W1 + ki * 512 + (half * 8) * 32 + sub;
        uint4 o;
        o.x = hpk(base[0],   base[32]);
        o.y = hpk(base[64],  base[96]);
        o.z = hpk(base[128], base[160]);
        o.w = hpk(base[192], base[224]);
        Wh1[(ki * 2 + half) * 32 + sub] = o;
    } else if (t < 1728 + 3456) {
        const int u = t - 1728;
        const int ki = u / 128, r = u % 128, qh = r >> 5, sub = r & 31;
        const int half = qh >> 1, q = qh & 1;
        const float* base = W2 + ki * 1024 + (half * 16 + q * 8) * 32 + sub;
        uint4 o;
        o.x = hpk(base[0],   base[32]);
        o.y = hpk(base[64],  base[96]);
        o.z = hpk(base[128], base[160]);
        o.w = hpk(base[192], base[224]);
        Wh2[((ki * 2 + half) * 2 + q) * 32 + sub] = o;
    } else if (t < 1728 + 3456 + 6912) {
        const int u = t - 5184;
        const int ki = u / 256, r = u % 256, q = r >> 6, lane = r & 63;
        const float* base = W3 + ki * 2048 + (q * 8) * 64 + lane;
        uint4 o;
        o.x = hpk(base[0],   base[64]);
        o.y = hpk(base[128], base[192]);
        o.z = hpk(base[256], base[320]);
        o.w = hpk(base[384], base[448]);
        Wh3[(ki * 4 + q) * 64 + lane] = o;
    }
}

// ---------------- feats fp32 -> fp16 pack ----------------
__global__ __launch_bounds__(256) void k_feat16(const float* __restrict__ F,
                                                unsigned* __restrict__ F16) {
    const int i = blockIdx.x * 256 + threadIdx.x;   // one float4 -> uint2
    if (i >= N_ * CIN / 4) return;
    const float4 v = ((const float4*)F)[i];
    uint2 o; o.x = hpk(v.x, v.y); o.y = hpk(v.z, v.w);
    ((uint2*)F16)[i] = o;
}

// ---------------- submanifold conv: one wave per POINT-PAIR, fp16 dot2 ------
template <int CI>
__global__ __launch_bounds__(256) void k_subm(const unsigned* __restrict__ X16,
                                              const int* __restrict__ coords,
                                              const int* __restrict__ grid,
                                              const uint4* __restrict__ Wh,
                                              const float* __restrict__ bias,
                                              float* __restrict__ Y) {
    constexpr int NQ = CI / 16;   // uint4 loads per tap per lane (1 or 2)
    const int pid  = (blockIdx.x * 256 + threadIdx.x) >> 6;
    const int lane = threadIdx.x & 63;
    const int sub  = lane & 31;
    const int half = lane >> 5;
    const int iA   = pid * 2;

    const int4 cA = *(const int4*)(coords + 4 * (size_t)iA);
    const int4 cB = *(const int4*)(coords + 4 * (size_t)(iA + 1));
    const int4 cc = half ? cB : cA;

    int nidx = -1;
    if (sub < 27) {
        const int nz = cc.y + sub / 9 - 1;
        const int ny = cc.z + (sub / 3) % 3 - 1;
        const int nx = cc.w + sub % 3 - 1;
        if ((unsigned)nz < (unsigned)D_ && (unsigned)ny < (unsigned)H_ &&
            (unsigned)nx < (unsigned)W_)
            nidx = grid[((cc.x * D_ + nz) * H_ + ny) * W_ + nx];
    }
    const unsigned long long act = __ballot(nidx >= 0);
    unsigned int actA = (unsigned int)(act & 0x7FFFFFFull);
    unsigned int actB = (unsigned int)((act >> 32) & 0x7FFFFFFull);

    float accA = 0.f, accB = 0.f;

    while (actA | actB) {
        if (actA) {
            const int ki = __builtin_ctz(actA); actA &= actA - 1;
            const int ni = __shfl(nidx, ki, 64);
            const uint4* __restrict__ f =
                (const uint4*)(X16 + (size_t)ni * (CI / 2) + half * (CI / 4));
            const uint4* __restrict__ wb = Wh + ((size_t)(ki * 2 + half)) * NQ * 32 + sub;
#pragma unroll
            for (int q = 0; q < NQ; ++q) {
                const uint4 fu = f[q];
                const uint4 wu = wb[q * 32];
                accA = dot2(fu.x, wu.x, accA);
                accA = dot2(fu.y, wu.y, accA);
                accA = dot2(fu.z, wu.z, accA);
                accA = dot2(fu.w, wu.w, accA);
            }
        }
        if (actB) {
            const int ki = __builtin_ctz(actB); actB &= actB - 1;
            const int ni = __shfl(nidx, ki + 32, 64);
            const uint4* __restrict__ f =
                (const uint4*)(X16 + (size_t)ni * (CI / 2) + half * (CI / 4));
            const uint4* __restrict__ wb = Wh + ((size_t)(ki * 2 + half)) * NQ * 32 + sub;
#pragma unroll
            for (int q = 0; q < NQ; ++q) {
                const uint4 fu = f[q];
                const uint4 wu = wb[q * 32];
                accB = dot2(fu.x, wu.x, accB);
                accB = dot2(fu.y, wu.y, accB);
                accB = dot2(fu.z, wu.z, accB);
                accB = dot2(fu.w, wu.w, accB);
            }
        }
    }

    accA += __shfl_xor(accA, 32, 64);     // combine ci halves
    accB += __shfl_xor(accB, 32, 64);
    const float outv = (half ? accB : accA) + bias[sub];
    Y[(size_t)(iA + half) * 32 + sub] = outv;
}

// ---------------- strided down conv: LDS grid rows + fp16 dot2 --------------
__global__ __launch_bounds__(256) void k_down(const unsigned* __restrict__ X16,
                                              const int* __restrict__ grid,
                                              const uint4* __restrict__ Wh3,
                                              const float* __restrict__ bias,
                                              float* __restrict__ Y,
                                              unsigned char* __restrict__ mask,
                                              float* __restrict__ slab0,
                                              int* __restrict__ nacts) {
    const int b    = blockIdx.x;
    const int swz  = (b & 7) * (NB_DOWN / 8) + (b >> 3);
    const int tid  = threadIdx.x;
    const int wv   = tid >> 6;
    const int lane = tid & 63;
    const int sub  = lane & 31;
    const int half = lane >> 5;

    const int vox0 = swz * 64;
    const int ox0  = vox0 & 127;      // 0 or 64
    int t = vox0 >> 7;
    const int oy = t & 127; t >>= 7;
    const int oz = t & 15;
    const int bb = t >> 4;

    __shared__ int   gl[9][132];
    __shared__ float sd[256];
    __shared__ int   scnt[4];

    const int gx0 = 2 * ox0 - 1;
    for (int e = tid; e < 9 * 132; e += 256) {
        const int r  = e / 132, xo = e % 132;
        const int z  = 2 * oz - 1 + r / 3;
        const int y  = 2 * oy - 1 + r % 3;
        const int x  = gx0 + xo;
        int v = -1;
        if ((unsigned)z < (unsigned)D_ && (unsigned)y < (unsigned)H_ &&
            (unsigned)x < (unsigned)W_ && xo < 129)
            v = grid[((bb * D_ + z) * H_ + y) * W_ + x];
        gl[r][xo] = v;
    }
    __syncthreads();

    const int dz = sub / 9, dy = (sub / 3) % 3, dx = sub % 3;
    const int row = (sub < 27) ? dz * 3 + dy : 0;

    const float bv = bias[lane];
    float s = 0.f, s2 = 0.f;
    int cnt = 0;

    for (int it = 0; it < 8; ++it) {
        const int pr = wv * 8 + it;                 // pair index 0..31
        const int xo = 2 * (pr * 2 + half) + dx;    // 0..128
        const int nidx = (sub < 27) ? gl[row][xo] : -1;

        const unsigned long long act = __ballot(nidx >= 0);
        unsigned int actA = (unsigned int)(act & 0x7FFFFFFull);
        unsigned int actB = (unsigned int)((act >> 32) & 0x7FFFFFFull);
        const int mkA = actA ? 1 : 0;
        const int mkB = actB ? 1 : 0;

        float accA = 0.f, accB = 0.f;
        while (actA | actB) {
            if (actA) {
                const int ki = __builtin_ctz(actA); actA &= actA - 1;
                const int ni = __builtin_amdgcn_readfirstlane(__shfl(nidx, ki, 64));
                const uint4* __restrict__ fS = (const uint4*)(X16 + (size_t)ni * 16);
                const uint4* __restrict__ wb = Wh3 + (size_t)ki * 256 + lane;
#pragma unroll
                for (int q = 0; q < 4; ++q) {
                    const uint4 fu = fS[q];
                    const uint4 wu = wb[q * 64];
                    accA = dot2(fu.x, wu.x, accA);
                    accA = dot2(fu.y, wu.y, accA);
                    accA = dot2(fu.z, wu.z, accA);
                    accA = dot2(fu.w, wu.w, accA);
                }
            }
            if (actB) {
                const int ki = __builtin_ctz(actB); actB &= actB - 1;
                const int ni = __builtin_amdgcn_readfirstlane(__shfl(nidx, ki + 32, 64));
                const uint4* __restrict__ fS = (const uint4*)(X16 + (size_t)ni * 16);
                const uint4* __restrict__ wb = Wh3 + (size_t)ki * 256 + lane;
#pragma unroll
                for (int q = 0; q < 4; ++q) {
                    const uint4 fu = fS[q];
                    const uint4 wu = wb[q * 64];
                    accB = dot2(fu.x, wu.x, accB);
                    accB = dot2(fu.y, wu.y, accB);
                    accB = dot2(fu.z, wu.z, accB);
                    accB = dot2(fu.w, wu.w, accB);
                }
            }
        }

        const int vA = vox0 + pr * 2;
        const float oA = mkA ? accA + bv : 0.f;
        const float oB = mkB ? accB + bv : 0.f;
        Y[(size_t)vA * COUT + lane]       = oA;
        Y[(size_t)(vA + 1) * COUT + lane] = oB;
        if (lane == 0) {
            mask[vA]     = (unsigned char)mkA;
            mask[vA + 1] = (unsigned char)mkB;
            cnt += mkA + mkB;
        }
        s  += oA + oB;
        s2 += oA * oA + oB * oB;
    }

    float* __restrict__ slab = slab0 + (size_t)(b & (NREP - 1)) * 128;
    sd[tid] = s;
    if (lane == 0) scnt[wv] = cnt;
    __syncthreads();
    if (tid < 64) atomicAdd(slab + tid, sd[tid] + sd[tid + 64] + sd[tid + 128] + sd[tid + 192]);
    __syncthreads();
    sd[tid] = s2;
    __syncthreads();
    if (tid < 64) atomicAdd(slab + 64 + tid, sd[tid] + sd[tid + 64] + sd[tid + 128] + sd[tid + 192]);
    if (tid == 0) atomicAdd(nacts + (b & (NREP - 1)), scnt[0] + scnt[1] + scnt[2] + scnt[3]);
}

// ---------------- per-channel sum / sumsq (stages 1,2) ----------------
template <int C>
__global__ __launch_bounds__(256) void k_stats(const float* __restrict__ Y,
                                               long n_elems,
                                               float* __restrict__ stats) {
    __shared__ float sdata[256];
    const int t = threadIdx.x;
    const long stride = (long)gridDim.x * 256;
    float s = 0.f, s2 = 0.f;
    for (long idx = (long)blockIdx.x * 256 + t; idx < n_elems; idx += stride) {
        const float v = Y[idx];
        s += v; s2 += v * v;
    }
    sdata[t] = s; __syncthreads();
    for (int off = 128; off >= C; off >>= 1) {
        if (t < off) sdata[t] += sdata[t + off];
        __syncthreads();
    }
    if (t < C) atomicAdd(stats + t, sdata[t]);
    __syncthreads();
    sdata[t] = s2; __syncthreads();
    for (int off = 128; off >= C; off >>= 1) {
        if (t < off) sdata[t] += sdata[t + off];
        __syncthreads();
    }
    if (t < C) atomicAdd(stats + C + t, sdata[t]);
}

// ---------------- finalize scale/shift (stages 1,2) ----------------
template <int C>
__global__ void k_finstats(const float* __restrict__ stats,
                           const float* __restrict__ g,
                           const float* __restrict__ be,
                           float nfix,
                           float* __restrict__ ss) {
    const int c = threadIdx.x;
    if (c >= C) return;
    const float n  = nfix;
    const float m  = stats[c] / n;
    const float v  = stats[C + c] / n - m * m;
    const float sc = g[c] * rsqrtf(v + EPSf);
    ss[c]     = sc;
    ss[C + c] = be[c] - m * sc;
}

// ---------------- finalize scale/shift (stage 3, folds NREP replicas) -------
__global__ void k_finstats3(const float* __restrict__ slab0,
                            const int* __restrict__ nacts,
                            const float* __restrict__ g,
                            const float* __restrict__ be,
                            float* __restrict__ ss) {
    const int c = threadIdx.x;   // 64 threads
    if (c >= 64) return;
    float sm = 0.f, s2 = 0.f;
    int na = 0;
    for (int r = 0; r < NREP; ++r) {
        sm += slab0[r * 128 + c];
        s2 += slab0[r * 128 + 64 + c];
        na += nacts[r];
    }
    const float n  = (float)(na > 0 ? na : 1);
    const float m  = sm / n;
    const float v  = s2 / n - m * m;
    const float sc = g[c] * rsqrtf(v + EPSf);
    ss[c]      = sc;
    ss[64 + c] = be[c] - m * sc;
}

// ---------------- normalize (BN+ReLU) -> packed fp16 ----------------
template <int C>
__global__ __launch_bounds__(256) void k_norm16(const float* __restrict__ Y,
                                                const float* __restrict__ ss,
                                                unsigned* __restrict__ Xo16, long n4) {
    const long t = (long)blockIdx.x * 256 + threadIdx.x;
    if (t >= n4) return;
    const float4 y = ((const float4*)Y)[t];
    const int ch = (int)((t * 4) % C);
    float ox = fmaxf(fmaf(y.x, ss[ch],     ss[C + ch]),     0.f);
    float oy = fmaxf(fmaf(y.y, ss[ch + 1], ss[C + ch + 1]), 0.f);
    float oz = fmaxf(fmaf(y.z, ss[ch + 2], ss[C + ch + 2]), 0.f);
    float ow = fmaxf(fmaf(y.w, ss[ch + 3], ss[C + ch + 3]), 0.f);
    uint2 o; o.x = hpk(ox, oy); o.y = hpk(oz, ow);
    ((uint2*)Xo16)[t] = o;
}

__global__ __launch_bounds__(256) void k_norm3(float* __restrict__ Y,
                                               const unsigned char* __restrict__ mask,
                                               const float* __restrict__ ss) {
    const long n4 = (long)M_ * COUT / 4;
    const long t = (long)blockIdx.x * 256 + threadIdx.x;
    if (t >= n4) return;
    const long vox = t >> 4;
    const float4 y = ((const float4*)Y)[t];
    const int ch = (int)((t * 4) & 63);
    float4 o;
    if (mask[vox]) {
        o.x = fmaxf(fmaf(y.x, ss[ch],     ss[64 + ch]),     0.f);
        o.y = fmaxf(fmaf(y.y, ss[ch + 1], ss[64 + ch + 1]), 0.f);
        o.z = fmaxf(fmaf(y.z, ss[ch + 2], ss[64 + ch + 2]), 0.f);
        o.w = fmaxf(fmaf(y.w, ss[ch + 3], ss[64 + ch + 3]), 0.f);
    } else {
        o.x = o.y = o.z = o.w = 0.f;
    }
    ((float4*)Y)[t] = o;
}

extern "C" void kernel_launch(void* const* d_in, const int* in_sizes, int n_in,
                              void* d_out, int out_size, void* d_ws, size_t ws_size,
                              hipStream_t stream) {
    const float* feats = (const float*)d_in[0];
    const int*   coords = (const int*)d_in[1];
    const float* W1 = (const float*)d_in[2];
    const float* b1 = (const float*)d_in[3];
    const float* g1 = (const float*)d_in[4];
    const float* be1 = (const float*)d_in[5];
    const float* W2 = (const float*)d_in[6];
    const float* b2 = (const float*)d_in[7];
    const float* g2 = (const float*)d_in[8];
    const float* be2 = (const float*)d_in[9];
    const float* W3 = (const float*)d_in[10];
    const float* b3 = (const float*)d_in[11];
    const float* g3 = (const float*)d_in[12];
    const float* be3 = (const float*)d_in[13];
    float* out = (float*)d_out;

    char* ws = (char*)d_ws;
    const size_t gridBytes = (size_t)B_ * D_ * H_ * W_ * 4;   // 16,777,216
    const size_t bufBytes  = (size_t)N_ * CMID * 4;           // 19,200,000 (fp32 conv out)
    const size_t bufHBytes = (size_t)N_ * CMID * 2;           // 9,600,000  (fp16 features)
    int*      grid   = (int*)ws;
    float*    bufA   = (float*)(ws + gridBytes);
    unsigned* bufH   = (unsigned*)(ws + gridBytes + bufBytes);
    unsigned* feat16 = (unsigned*)(ws + gridBytes + bufBytes + bufHBytes);
    unsigned char* mask = (unsigned char*)(ws + gridBytes + bufBytes + bufHBytes +
                                           (size_t)N_ * CIN * 2);
    float* stats = (float*)(ws + gridBytes + bufBytes + bufHBytes +
                            (size_t)N_ * CIN * 2 + (size_t)M_);

    float* st1   = stats;                 // 32 sum + 32 sumsq
    float* st2   = stats + 64;
    float* ss1   = stats + 260;
    float* ss2   = stats + 324;
    float* ss3   = stats + 388;
    float* slab3 = stats + 1024;          // NREP x 128 floats
    int*   nacts = (int*)(stats + 1024 + NREP * 128);   // NREP ints
    uint4* Wh1 = (uint4*)(stats + 16384);               // 1728 uint4
    uint4* Wh2 = Wh1 + 1728;                            // 3456 uint4
    uint4* Wh3 = Wh2 + 3456;                            // 6912 uint4

    hipMemsetAsync(grid, 0xFF, gridBytes, stream);
    hipMemsetAsync(stats, 0, 256 * 4, stream);                        // st1,st2
    hipMemsetAsync(stats + 1024, 0, (NREP * 128 + NREP) * 4, stream); // slab3+nacts

    k_scatter<<<(N_ + 255) / 256, 256, 0, stream>>>(coords, grid);
    k_twisth<<<(12096 + 255) / 256, 256, 0, stream>>>(W1, W2, W3, Wh1, Wh2, Wh3);
    k_feat16<<<(N_ * CIN / 4 + 255) / 256, 256, 0, stream>>>(feats, feat16);

    const int nb_subm = 75000 / 4;   // 18750, exact (pairs, 4 waves/block)
    k_subm<CIN><<<nb_subm, 256, 0, stream>>>(feat16, coords, grid, Wh1, b1, bufA);
    k_stats<CMID><<<512, 256, 0, stream>>>(bufA, (long)N_ * CMID, st1);
    k_finstats<CMID><<<1, 64, 0, stream>>>(st1, g1, be1, (float)N_, ss1);
    k_norm16<CMID><<<(N_ * CMID / 4 + 255) / 256, 256, 0, stream>>>(bufA, ss1, bufH,
                                                                    (long)N_ * CMID / 4);

    k_subm<CMID><<<nb_subm, 256, 0, stream>>>(bufH, coords, grid, Wh2, b2, bufA);
    k_stats<CMID><<<512, 256, 0, stream>>>(bufA, (long)N_ * CMID, st2);
    k_finstats<CMID><<<1, 64, 0, stream>>>(st2, g2, be2, (float)N_, ss2);
    k_norm16<CMID><<<(N_ * CMID / 4 + 255) / 256, 256, 0, stream>>>(bufA, ss2, bufH,
                                                                    (long)N_ * CMID / 4);

    k_down<<<NB_DOWN, 256, 0, stream>>>(bufH, grid, Wh3, b3, out, mask, slab3, nacts);
    k_finstats3<<<1, 64, 0, stream>>>(slab3, nacts, g3, be3, ss3);
    k_norm3<<<(M_ * COUT / 4) / 256, 256, 0, stream>>>(out, mask, ss3);
}

// Round 10
// 264.973 us; speedup vs baseline: 2.0781x; 1.0896x over previous
//
#include <hip/hip_runtime.h>

#define B_   2
#define D_   32
#define H_   256
#define W_   256
#define N_   150000
#define CIN  16
#define CMID 32
#define COUT 64
#define DO_  16
#define HO_  128
#define WO_  128
#define M_   (B_*DO_*HO_*WO_)   /* 524288 */
#define EPSf 1e-5f
#define NB_DOWN 8192             /* k_down blocks; %8==0, 64 voxels per block */
#define NREP 64                  /* stats slabs (atomic de-contention) */

typedef _Float16 h2 __attribute__((ext_vector_type(2)));
__device__ inline h2 as_h2(unsigned u) { union { unsigned u; h2 h; } x; x.u = u; return x.h; }

#if defined(__has_builtin) && __has_builtin(__builtin_amdgcn_fdot2)
__device__ inline float dot2(unsigned f, unsigned w, float acc) {
    return __builtin_amdgcn_fdot2(as_h2(f), as_h2(w), acc, false);
}
#else
__device__ inline float dot2(unsigned f, unsigned w, float acc) {
    const h2 a = as_h2(f), b = as_h2(w);
    return fmaf((float)a.x, (float)b.x, fmaf((float)a.y, (float)b.y, acc));
}
#endif

// pack two floats into one dword of fp16 (RNE via _Float16 cast)
__device__ inline unsigned hpk(float a, float b) {
    union { _Float16 h[2]; unsigned u; } x;
    x.h[0] = (_Float16)a; x.h[1] = (_Float16)b; return x.u;
}

// ---------------- grid scatter ----------------
__global__ __launch_bounds__(256) void k_scatter(const int* __restrict__ coords,
                                                 int* __restrict__ grid) {
    int i = blockIdx.x * 256 + threadIdx.x;
    if (i >= N_) return;
    const int4 c = *(const int4*)(coords + 4 * (size_t)i);
    grid[((c.x * D_ + c.y) * H_ + c.z) * W_ + c.w] = i;
}

// ---------------- weight transpose+pack to fp16 pairs ----------------
__global__ __launch_bounds__(256) void k_twisth(const float* __restrict__ W1,
                                                const float* __restrict__ W2,
                                                const float* __restrict__ W3,
                                                uint4* __restrict__ Wh1,
                                                uint4* __restrict__ Wh2,
                                                uint4* __restrict__ Wh3) {
    const int t = blockIdx.x * 256 + threadIdx.x;
    if (t < 1728) {
        const int ki = t / 64, r = t % 64, half = r >> 5, sub = r & 31;
        const float* base = W1 + ki * 512 + (half * 8) * 32 + sub;
        uint4 o;
        o.x = hpk(base[0],   base[32]);
        o.y = hpk(base[64],  base[96]);
        o.z = hpk(base[128], base[160]);
        o.w = hpk(base[192], base[224]);
        Wh1[(ki * 2 + half) * 32 + sub] = o;
    } else if (t < 1728 + 3456) {
        const int u = t - 1728;
        const int ki = u / 128, r = u % 128, qh = r >> 5, sub = r & 31;
        const int half = qh >> 1, q = qh & 1;
        const float* base = W2 + ki * 1024 + (half * 16 + q * 8) * 32 + sub;
        uint4 o;
        o.x = hpk(base[0],   base[32]);
        o.y = hpk(base[64],  base[96]);
        o.z = hpk(base[128], base[160]);
        o.w = hpk(base[192], base[224]);
        Wh2[((ki * 2 + half) * 2 + q) * 32 + sub] = o;
    } else if (t < 1728 + 3456 + 6912) {
        const int u = t - 5184;
        const int ki = u / 256, r = u % 256, q = r >> 6, lane = r & 63;
        const float* base = W3 + ki * 2048 + (q * 8) * 64 + lane;
        uint4 o;
        o.x = hpk(base[0],   base[64]);
        o.y = hpk(base[128], base[192]);
        o.z = hpk(base[256], base[320]);
        o.w = hpk(base[384], base[448]);
        Wh3[(ki * 4 + q) * 64 + lane] = o;
    }
}

// ---------------- feats fp32 -> fp16 pack ----------------
__global__ __launch_bounds__(256) void k_feat16(const float* __restrict__ F,
                                                unsigned* __restrict__ F16) {
    const int i = blockIdx.x * 256 + threadIdx.x;   // one float4 -> uint2
    if (i >= N_ * CIN / 4) return;
    const float4 v = ((const float4*)F)[i];
    uint2 o; o.x = hpk(v.x, v.y); o.y = hpk(v.z, v.w);
    ((uint2*)F16)[i] = o;
}

// ---------------- submanifold conv: one wave per POINT-PAIR, fp16 dot2 ------
template <int CI>
__global__ __launch_bounds__(256) void k_subm(const unsigned* __restrict__ X16,
                                              const int* __restrict__ coords,
                                              const int* __restrict__ grid,
                                              const uint4* __restrict__ Wh,
                                              const float* __restrict__ bias,
                                              float* __restrict__ Y) {
    constexpr int NQ = CI / 16;   // uint4 loads per tap per lane (1 or 2)
    const int pid  = (blockIdx.x * 256 + threadIdx.x) >> 6;
    const int lane = threadIdx.x & 63;
    const int sub  = lane & 31;
    const int half = lane >> 5;
    const int iA   = pid * 2;

    const int4 cA = *(const int4*)(coords + 4 * (size_t)iA);
    const int4 cB = *(const int4*)(coords + 4 * (size_t)(iA + 1));
    const int4 cc = half ? cB : cA;

    int nidx = -1;
    if (sub < 27) {
        const int nz = cc.y + sub / 9 - 1;
        const int ny = cc.z + (sub / 3) % 3 - 1;
        const int nx = cc.w + sub % 3 - 1;
        if ((unsigned)nz < (unsigned)D_ && (unsigned)ny < (unsigned)H_ &&
            (unsigned)nx < (unsigned)W_)
            nidx = grid[((cc.x * D_ + nz) * H_ + ny) * W_ + nx];
    }
    const unsigned long long act = __ballot(nidx >= 0);
    unsigned int actA = (unsigned int)(act & 0x7FFFFFFull);
    unsigned int actB = (unsigned int)((act >> 32) & 0x7FFFFFFull);

    float accA = 0.f, accB = 0.f;

    while (actA | actB) {
        if (actA) {
            const int ki = __builtin_ctz(actA); actA &= actA - 1;
            const int ni = __shfl(nidx, ki, 64);
            const uint4* __restrict__ f =
                (const uint4*)(X16 + (size_t)ni * (CI / 2) + half * (CI / 4));
            const uint4* __restrict__ wb = Wh + ((size_t)(ki * 2 + half)) * NQ * 32 + sub;
#pragma unroll
            for (int q = 0; q < NQ; ++q) {
                const uint4 fu = f[q];
                const uint4 wu = wb[q * 32];
                accA = dot2(fu.x, wu.x, accA);
                accA = dot2(fu.y, wu.y, accA);
                accA = dot2(fu.z, wu.z, accA);
                accA = dot2(fu.w, wu.w, accA);
            }
        }
        if (actB) {
            const int ki = __builtin_ctz(actB); actB &= actB - 1;
            const int ni = __shfl(nidx, ki + 32, 64);
            const uint4* __restrict__ f =
                (const uint4*)(X16 + (size_t)ni * (CI / 2) + half * (CI / 4));
            const uint4* __restrict__ wb = Wh + ((size_t)(ki * 2 + half)) * NQ * 32 + sub;
#pragma unroll
            for (int q = 0; q < NQ; ++q) {
                const uint4 fu = f[q];
                const uint4 wu = wb[q * 32];
                accB = dot2(fu.x, wu.x, accB);
                accB = dot2(fu.y, wu.y, accB);
                accB = dot2(fu.z, wu.z, accB);
                accB = dot2(fu.w, wu.w, accB);
            }
        }
    }

    accA += __shfl_xor(accA, 32, 64);     // combine ci halves
    accB += __shfl_xor(accB, 32, 64);
    const float outv = (half ? accB : accA) + bias[sub];
    Y[(size_t)(iA + half) * 32 + sub] = outv;
}

// ---------------- strided down conv: LDS grid rows + fp16 dot2, fp16 out ----
__global__ __launch_bounds__(256) void k_down(const unsigned* __restrict__ X16,
                                              const int* __restrict__ grid,
                                              const uint4* __restrict__ Wh3,
                                              const float* __restrict__ bias,
                                              _Float16* __restrict__ Yh,
                                              unsigned char* __restrict__ mask,
                                              float* __restrict__ slab0,
                                              int* __restrict__ nacts) {
    const int b    = blockIdx.x;
    const int swz  = (b & 7) * (NB_DOWN / 8) + (b >> 3);
    const int tid  = threadIdx.x;
    const int wv   = tid >> 6;
    const int lane = tid & 63;
    const int sub  = lane & 31;
    const int half = lane >> 5;

    const int vox0 = swz * 64;
    const int ox0  = vox0 & 127;      // 0 or 64
    int t = vox0 >> 7;
    const int oy = t & 127; t >>= 7;
    const int oz = t & 15;
    const int bb = t >> 4;

    __shared__ int   gl[9][132];
    __shared__ float sd[256];
    __shared__ int   scnt[4];

    const int gx0 = 2 * ox0 - 1;
    for (int e = tid; e < 9 * 132; e += 256) {
        const int r  = e / 132, xo = e % 132;
        const int z  = 2 * oz - 1 + r / 3;
        const int y  = 2 * oy - 1 + r % 3;
        const int x  = gx0 + xo;
        int v = -1;
        if ((unsigned)z < (unsigned)D_ && (unsigned)y < (unsigned)H_ &&
            (unsigned)x < (unsigned)W_ && xo < 129)
            v = grid[((bb * D_ + z) * H_ + y) * W_ + x];
        gl[r][xo] = v;
    }
    __syncthreads();

    const int dz = sub / 9, dy = (sub / 3) % 3, dx = sub % 3;
    const int row = (sub < 27) ? dz * 3 + dy : 0;

    const float bv = bias[lane];
    float s = 0.f, s2 = 0.f;
    int cnt = 0;

    for (int it = 0; it < 8; ++it) {
        const int pr = wv * 8 + it;                 // pair index 0..31
        const int xo = 2 * (pr * 2 + half) + dx;    // 0..128
        const int nidx = (sub < 27) ? gl[row][xo] : -1;

        const unsigned long long act = __ballot(nidx >= 0);
        unsigned int actA = (unsigned int)(act & 0x7FFFFFFull);
        unsigned int actB = (unsigned int)((act >> 32) & 0x7FFFFFFull);
        const int mkA = actA ? 1 : 0;
        const int mkB = actB ? 1 : 0;

        float accA = 0.f, accB = 0.f;
        while (actA | actB) {
            if (actA) {
                const int ki = __builtin_ctz(actA); actA &= actA - 1;
                const int ni = __builtin_amdgcn_readfirstlane(__shfl(nidx, ki, 64));
                const uint4* __restrict__ fS = (const uint4*)(X16 + (size_t)ni * 16);
                const uint4* __restrict__ wb = Wh3 + (size_t)ki * 256 + lane;
#pragma unroll
                for (int q = 0; q < 4; ++q) {
                    const uint4 fu = fS[q];
                    const uint4 wu = wb[q * 64];
                    accA = dot2(fu.x, wu.x, accA);
                    accA = dot2(fu.y, wu.y, accA);
                    accA = dot2(fu.z, wu.z, accA);
                    accA = dot2(fu.w, wu.w, accA);
                }
            }
            if (actB) {
                const int ki = __builtin_ctz(actB); actB &= actB - 1;
                const int ni = __builtin_amdgcn_readfirstlane(__shfl(nidx, ki + 32, 64));
                const uint4* __restrict__ fS = (const uint4*)(X16 + (size_t)ni * 16);
                const uint4* __restrict__ wb = Wh3 + (size_t)ki * 256 + lane;
#pragma unroll
                for (int q = 0; q < 4; ++q) {
                    const uint4 fu = fS[q];
                    const uint4 wu = wb[q * 64];
                    accB = dot2(fu.x, wu.x, accB);
                    accB = dot2(fu.y, wu.y, accB);
                    accB = dot2(fu.z, wu.z, accB);
                    accB = dot2(fu.w, wu.w, accB);
                }
            }
        }

        const int vA = vox0 + pr * 2;
        const float oA = mkA ? accA + bv : 0.f;
        const float oB = mkB ? accB + bv : 0.f;
        Yh[(size_t)vA * COUT + lane]       = (_Float16)oA;
        Yh[(size_t)(vA + 1) * COUT + lane] = (_Float16)oB;
        if (lane == 0) {
            mask[vA]     = (unsigned char)mkA;
            mask[vA + 1] = (unsigned char)mkB;
            cnt += mkA + mkB;
        }
        s  += oA + oB;
        s2 += oA * oA + oB * oB;
    }

    float* __restrict__ slab = slab0 + (size_t)(b & (NREP - 1)) * 128;
    sd[tid] = s;
    if (lane == 0) scnt[wv] = cnt;
    __syncthreads();
    if (tid < 64) atomicAdd(slab + tid, sd[tid] + sd[tid + 64] + sd[tid + 128] + sd[tid + 192]);
    __syncthreads();
    sd[tid] = s2;
    __syncthreads();
    if (tid < 64) atomicAdd(slab + 64 + tid, sd[tid] + sd[tid + 64] + sd[tid + 128] + sd[tid + 192]);
    if (tid == 0) atomicAdd(nacts + (b & (NREP - 1)), scnt[0] + scnt[1] + scnt[2] + scnt[3]);
}

// ------- per-channel sum/sumsq (stages 1,2) -> NREP slabs (de-contended) ----
template <int C>
__global__ __launch_bounds__(256) void k_stats(const float* __restrict__ Y,
                                               long n_elems,
                                               float* __restrict__ slab0) {
    __shared__ float sdata[256];
    const int t = threadIdx.x;
    const long stride = (long)gridDim.x * 256;
    float s = 0.f, s2 = 0.f;
    for (long idx = (long)blockIdx.x * 256 + t; idx < n_elems; idx += stride) {
        const float v = Y[idx];
        s += v; s2 += v * v;
    }
    float* __restrict__ slab = slab0 + (size_t)(blockIdx.x & (NREP - 1)) * 2 * C;
    sdata[t] = s; __syncthreads();
    for (int off = 128; off >= C; off >>= 1) {
        if (t < off) sdata[t] += sdata[t + off];
        __syncthreads();
    }
    if (t < C) atomicAdd(slab + t, sdata[t]);
    __syncthreads();
    sdata[t] = s2; __syncthreads();
    for (int off = 128; off >= C; off >>= 1) {
        if (t < off) sdata[t] += sdata[t + off];
        __syncthreads();
    }
    if (t < C) atomicAdd(slab + C + t, sdata[t]);
}

// ---------------- finalize scale/shift from NREP slabs (stages 1,2) ---------
template <int C>
__global__ void k_finslab(const float* __restrict__ slab0,
                          const float* __restrict__ g,
                          const float* __restrict__ be,
                          float n, float* __restrict__ ss) {
    const int c = threadIdx.x;
    if (c >= C) return;
    float sm = 0.f, s2 = 0.f;
    for (int r = 0; r < NREP; ++r) {
        sm += slab0[r * 2 * C + c];
        s2 += slab0[r * 2 * C + C + c];
    }
    const float m  = sm / n;
    const float v  = s2 / n - m * m;
    const float sc = g[c] * rsqrtf(v + EPSf);
    ss[c]     = sc;
    ss[C + c] = be[c] - m * sc;
}

// ---------------- finalize scale/shift (stage 3, folds NREP replicas) -------
__global__ void k_finstats3(const float* __restrict__ slab0,
                            const int* __restrict__ nacts,
                            const float* __restrict__ g,
                            const float* __restrict__ be,
                            float* __restrict__ ss) {
    const int c = threadIdx.x;   // 64 threads
    if (c >= 64) return;
    float sm = 0.f, s2 = 0.f;
    int na = 0;
    for (int r = 0; r < NREP; ++r) {
        sm += slab0[r * 128 + c];
        s2 += slab0[r * 128 + 64 + c];
        na += nacts[r];
    }
    const float n  = (float)(na > 0 ? na : 1);
    const float m  = sm / n;
    const float v  = s2 / n - m * m;
    const float sc = g[c] * rsqrtf(v + EPSf);
    ss[c]      = sc;
    ss[64 + c] = be[c] - m * sc;
}

// ---------------- normalize (BN+ReLU) -> packed fp16 ----------------
template <int C>
__global__ __launch_bounds__(256) void k_norm16(const float* __restrict__ Y,
                                                const float* __restrict__ ss,
                                                unsigned* __restrict__ Xo16, long n4) {
    const long t = (long)blockIdx.x * 256 + threadIdx.x;
    if (t >= n4) return;
    const float4 y = ((const float4*)Y)[t];
    const int ch = (int)((t * 4) % C);
    float ox = fmaxf(fmaf(y.x, ss[ch],     ss[C + ch]),     0.f);
    float oy = fmaxf(fmaf(y.y, ss[ch + 1], ss[C + ch + 1]), 0.f);
    float oz = fmaxf(fmaf(y.z, ss[ch + 2], ss[C + ch + 2]), 0.f);
    float ow = fmaxf(fmaf(y.w, ss[ch + 3], ss[C + ch + 3]), 0.f);
    uint2 o; o.x = hpk(ox, oy); o.y = hpk(oz, ow);
    ((uint2*)Xo16)[t] = o;
}

// ---------------- stage-3 normalize: fp16 in, fp32 out ----------------
__global__ __launch_bounds__(256) void k_norm3(const _Float16* __restrict__ Yh,
                                               const unsigned char* __restrict__ mask,
                                               const float* __restrict__ ss,
                                               float* __restrict__ out) {
    const long n4 = (long)M_ * COUT / 4;
    const long t = (long)blockIdx.x * 256 + threadIdx.x;
    if (t >= n4) return;
    const long vox = t >> 4;
    const int ch = (int)((t * 4) & 63);
    float4 o;
    if (mask[vox]) {
        const uint2 yu = *(const uint2*)(Yh + t * 4);
        const h2 ylo = as_h2(yu.x), yhi = as_h2(yu.y);
        o.x = fmaxf(fmaf((float)ylo.x, ss[ch],     ss[64 + ch]),     0.f);
        o.y = fmaxf(fmaf((float)ylo.y, ss[ch + 1], ss[64 + ch + 1]), 0.f);
        o.z = fmaxf(fmaf((float)yhi.x, ss[ch + 2], ss[64 + ch + 2]), 0.f);
        o.w = fmaxf(fmaf((float)yhi.y, ss[ch + 3], ss[64 + ch + 3]), 0.f);
    } else {
        o.x = o.y = o.z = o.w = 0.f;
    }
    ((float4*)out)[t] = o;
}

extern "C" void kernel_launch(void* const* d_in, const int* in_sizes, int n_in,
                              void* d_out, int out_size, void* d_ws, size_t ws_size,
                              hipStream_t stream) {
    const float* feats = (const float*)d_in[0];
    const int*   coords = (const int*)d_in[1];
    const float* W1 = (const float*)d_in[2];
    const float* b1 = (const float*)d_in[3];
    const float* g1 = (const float*)d_in[4];
    const float* be1 = (const float*)d_in[5];
    const float* W2 = (const float*)d_in[6];
    const float* b2 = (const float*)d_in[7];
    const float* g2 = (const float*)d_in[8];
    const float* be2 = (const float*)d_in[9];
    const float* W3 = (const float*)d_in[10];
    const float* b3 = (const float*)d_in[11];
    const float* g3 = (const float*)d_in[12];
    const float* be3 = (const float*)d_in[13];
    float* out = (float*)d_out;

    char* ws = (char*)d_ws;
    const size_t gridBytes = (size_t)B_ * D_ * H_ * W_ * 4;   // 16,777,216
    const size_t bufBytes  = (size_t)N_ * CMID * 4;           // 19,200,000 (fp32 conv out)
    const size_t bufHBytes = (size_t)N_ * CMID * 2;           // 9,600,000  (fp16 features)
    const size_t YhBytes   = (size_t)M_ * COUT * 2;           // 67,108,864 (fp16 stage-3 out)
    int*       grid   = (int*)ws;
    float*     bufA   = (float*)(ws + gridBytes);
    unsigned*  bufH   = (unsigned*)(ws + gridBytes + bufBytes);
    unsigned*  feat16 = (unsigned*)(ws + gridBytes + bufBytes + bufHBytes);
    _Float16*  Yh     = (_Float16*)(ws + gridBytes + bufBytes + bufHBytes +
                                    (size_t)N_ * CIN * 2);
    unsigned char* mask = (unsigned char*)(ws + gridBytes + bufBytes + bufHBytes +
                                           (size_t)N_ * CIN * 2 + YhBytes);
    float* stats = (float*)(ws + gridBytes + bufBytes + bufHBytes +
                            (size_t)N_ * CIN * 2 + YhBytes + (size_t)M_);

    float* ss1   = stats;                 // 64
    float* ss2   = stats + 64;            // 64
    float* ss3   = stats + 128;           // 128
    float* slab1 = stats + 1024;                        // NREP*64
    float* slab2 = stats + 1024 + NREP * 64;            // NREP*64
    float* slab3 = stats + 1024 + NREP * 128;           // NREP*128
    int*   nacts = (int*)(stats + 1024 + NREP * 256);   // NREP ints
    uint4* Wh1 = (uint4*)(stats + 32768);               // 1728 uint4
    uint4* Wh2 = Wh1 + 1728;                            // 3456 uint4
    uint4* Wh3 = Wh2 + 3456;                            // 6912 uint4

    hipMemsetAsync(grid, 0xFF, gridBytes, stream);
    hipMemsetAsync(stats + 1024, 0, (NREP * 256 + NREP) * 4, stream); // slabs+nacts

    k_scatter<<<(N_ + 255) / 256, 256, 0, stream>>>(coords, grid);
    k_twisth<<<(12096 + 255) / 256, 256, 0, stream>>>(W1, W2, W3, Wh1, Wh2, Wh3);
    k_feat16<<<(N_ * CIN / 4 + 255) / 256, 256, 0, stream>>>(feats, feat16);

    const int nb_subm = 75000 / 4;   // 18750, exact (pairs, 4 waves/block)
    k_subm<CIN><<<nb_subm, 256, 0, stream>>>(feat16, coords, grid, Wh1, b1, bufA);
    k_stats<CMID><<<512, 256, 0, stream>>>(bufA, (long)N_ * CMID, slab1);
    k_finslab<CMID><<<1, 64, 0, stream>>>(slab1, g1, be1, (float)N_, ss1);
    k_norm16<CMID><<<(N_ * CMID / 4 + 255) / 256, 256, 0, stream>>>(bufA, ss1, bufH,
                                                                    (long)N_ * CMID / 4);

    k_subm<CMID><<<nb_subm, 256, 0, stream>>>(bufH, coords, grid, Wh2, b2, bufA);
    k_stats<CMID><<<512, 256, 0, stream>>>(bufA, (long)N_ * CMID, slab2);
    k_finslab<CMID><<<1, 64, 0, stream>>>(slab2, g2, be2, (float)N_, ss2);
    k_norm16<CMID><<<(N_ * CMID / 4 + 255) / 256, 256, 0, stream>>>(bufA, ss2, bufH,
                                                                    (long)N_ * CMID / 4);

    k_down<<<NB_DOWN, 256, 0, stream>>>(bufH, grid, Wh3, b3, Yh, mask, slab3, nacts);
    k_finstats3<<<1, 64, 0, stream>>>(slab3, nacts, g3, be3, ss3);
    k_norm3<<<(M_ * COUT / 4) / 256, 256, 0, stream>>>(Yh, mask, ss3, out);
}

// Round 11
// 239.684 us; speedup vs baseline: 2.2974x; 1.1055x over previous
//
#include <hip/hip_runtime.h>

#define B_   2
#define D_   32
#define H_   256
#define W_   256
#define N_   150000
#define CIN  16
#define CMID 32
#define COUT 64
#define DO_  16
#define HO_  128
#define WO_  128
#define M_   (B_*DO_*HO_*WO_)   /* 524288 */
#define EPSf 1e-5f
#define NB_DOWN 8192             /* k_down blocks; %8==0, 64 voxels per block */
#define NREP 64                  /* stats slabs (atomic de-contention) */

typedef _Float16 h2 __attribute__((ext_vector_type(2)));
__device__ inline h2 as_h2(unsigned u) { union { unsigned u; h2 h; } x; x.u = u; return x.h; }

#if defined(__has_builtin) && __has_builtin(__builtin_amdgcn_fdot2)
__device__ inline float dot2(unsigned f, unsigned w, float acc) {
    return __builtin_amdgcn_fdot2(as_h2(f), as_h2(w), acc, false);
}
#else
__device__ inline float dot2(unsigned f, unsigned w, float acc) {
    const h2 a = as_h2(f), b = as_h2(w);
    return fmaf((float)a.x, (float)b.x, fmaf((float)a.y, (float)b.y, acc));
}
#endif

// pack two floats into one dword of fp16 (RNE via _Float16 cast)
__device__ inline unsigned hpk(float a, float b) {
    union { _Float16 h[2]; unsigned u; } x;
    x.h[0] = (_Float16)a; x.h[1] = (_Float16)b; return x.u;
}

// ---------------- grid scatter ----------------
__global__ __launch_bounds__(256) void k_scatter(const int* __restrict__ coords,
                                                 int* __restrict__ grid) {
    int i = blockIdx.x * 256 + threadIdx.x;
    if (i >= N_) return;
    const int4 c = *(const int4*)(coords + 4 * (size_t)i);
    grid[((c.x * D_ + c.y) * H_ + c.z) * W_ + c.w] = i;
}

// ---------------- weight transpose+pack to fp16 pairs ----------------
__global__ __launch_bounds__(256) void k_twisth(const float* __restrict__ W1,
                                                const float* __restrict__ W2,
                                                const float* __restrict__ W3,
                                                uint4* __restrict__ Wh1,
                                                uint4* __restrict__ Wh2,
                                                uint4* __restrict__ Wh3) {
    const int t = blockIdx.x * 256 + threadIdx.x;
    if (t < 1728) {
        const int ki = t / 64, r = t % 64, half = r >> 5, sub = r & 31;
        const float* base = W1 + ki * 512 + (half * 8) * 32 + sub;
        uint4 o;
        o.x = hpk(base[0],   base[32]);
        o.y = hpk(base[64],  base[96]);
        o.z = hpk(base[128], base[160]);
        o.w = hpk(base[192], base[224]);
        Wh1[(ki * 2 + half) * 32 + sub] = o;
    } else if (t < 1728 + 3456) {
        const int u = t - 1728;
        const int ki = u / 128, r = u % 128, qh = r >> 5, sub = r & 31;
        const int half = qh >> 1, q = qh & 1;
        const float* base = W2 + ki * 1024 + (half * 16 + q * 8) * 32 + sub;
        uint4 o;
        o.x = hpk(base[0],   base[32]);
        o.y = hpk(base[64],  base[96]);
        o.z = hpk(base[128], base[160]);
        o.w = hpk(base[192], base[224]);
        Wh2[((ki * 2 + half) * 2 + q) * 32 + sub] = o;
    } else if (t < 1728 + 3456 + 6912) {
        const int u = t - 5184;
        const int ki = u / 256, r = u % 256, q = r >> 6, lane = r & 63;
        const float* base = W3 + ki * 2048 + (q * 8) * 64 + lane;
        uint4 o;
        o.x = hpk(base[0],   base[64]);
        o.y = hpk(base[128], base[192]);
        o.z = hpk(base[256], base[320]);
        o.w = hpk(base[384], base[448]);
        Wh3[(ki * 4 + q) * 64 + lane] = o;
    }
}

// ---------------- feats fp32 -> fp16 pack ----------------
__global__ __launch_bounds__(256) void k_feat16(const float* __restrict__ F,
                                                unsigned* __restrict__ F16) {
    const int i = blockIdx.x * 256 + threadIdx.x;   // one float4 -> uint2
    if (i >= N_ * CIN / 4) return;
    const float4 v = ((const float4*)F)[i];
    uint2 o; o.x = hpk(v.x, v.y); o.y = hpk(v.z, v.w);
    ((uint2*)F16)[i] = o;
}

// ------- submanifold conv: 4 points/wave, branched 4-chain, fused stats -----
// Writes fp16 PRE-norm output; stats (fp32 exact) into NREP slabs.
template <int CI>
__global__ __launch_bounds__(256) void k_subm(const unsigned* __restrict__ X16,
                                              const int* __restrict__ coords,
                                              const int* __restrict__ grid,
                                              const uint4* __restrict__ Wh,
                                              const float* __restrict__ bias,
                                              _Float16* __restrict__ Yp,
                                              float* __restrict__ slab0) {
    constexpr int NQ = CI / 16;   // uint4 loads per tap per lane (1 or 2)
    const int wid  = (blockIdx.x * 256 + threadIdx.x) >> 6;
    const int lane = threadIdx.x & 63;
    const int sub  = lane & 31;
    const int half = lane >> 5;
    const int i0   = wid * 4;

    int nidx01 = -1, nidx23 = -1;
    {
        const int4 cc = *(const int4*)(coords + 4 * (size_t)(i0 + half));
        if (sub < 27) {
            const int nz = cc.y + sub / 9 - 1;
            const int ny = cc.z + (sub / 3) % 3 - 1;
            const int nx = cc.w + sub % 3 - 1;
            if ((unsigned)nz < (unsigned)D_ && (unsigned)ny < (unsigned)H_ &&
                (unsigned)nx < (unsigned)W_)
                nidx01 = grid[((cc.x * D_ + nz) * H_ + ny) * W_ + nx];
        }
    }
    {
        const int4 cc = *(const int4*)(coords + 4 * (size_t)(i0 + 2 + half));
        if (sub < 27) {
            const int nz = cc.y + sub / 9 - 1;
            const int ny = cc.z + (sub / 3) % 3 - 1;
            const int nx = cc.w + sub % 3 - 1;
            if ((unsigned)nz < (unsigned)D_ && (unsigned)ny < (unsigned)H_ &&
                (unsigned)nx < (unsigned)W_)
                nidx23 = grid[((cc.x * D_ + nz) * H_ + ny) * W_ + nx];
        }
    }
    const unsigned long long a01 = __ballot(nidx01 >= 0);
    const unsigned long long a23 = __ballot(nidx23 >= 0);
    unsigned m0 = (unsigned)a01 & 0x7FFFFFFu;
    unsigned m1 = (unsigned)(a01 >> 32) & 0x7FFFFFFu;
    unsigned m2 = (unsigned)a23 & 0x7FFFFFFu;
    unsigned m3 = (unsigned)(a23 >> 32) & 0x7FFFFFFu;

    float acc0 = 0.f, acc1 = 0.f, acc2 = 0.f, acc3 = 0.f;

    auto tap = [&](int ki, int ni, float& acc) {
        const uint4* __restrict__ f =
            (const uint4*)(X16 + (size_t)ni * (CI / 2) + half * (CI / 4));
        const uint4* __restrict__ wb = Wh + ((size_t)(ki * 2 + half)) * NQ * 32 + sub;
#pragma unroll
        for (int q = 0; q < NQ; ++q) {
            const uint4 fu = f[q];
            const uint4 wu = wb[q * 32];
            acc = dot2(fu.x, wu.x, acc);
            acc = dot2(fu.y, wu.y, acc);
            acc = dot2(fu.z, wu.z, acc);
            acc = dot2(fu.w, wu.w, acc);
        }
    };

    while (m0 | m1 | m2 | m3) {
        if (m0) { const int ki = __builtin_ctz(m0); m0 &= m0 - 1;
                  tap(ki, __shfl(nidx01, ki, 64),      acc0); }
        if (m1) { const int ki = __builtin_ctz(m1); m1 &= m1 - 1;
                  tap(ki, __shfl(nidx01, ki + 32, 64), acc1); }
        if (m2) { const int ki = __builtin_ctz(m2); m2 &= m2 - 1;
                  tap(ki, __shfl(nidx23, ki, 64),      acc2); }
        if (m3) { const int ki = __builtin_ctz(m3); m3 &= m3 - 1;
                  tap(ki, __shfl(nidx23, ki + 32, 64), acc3); }
    }

    acc0 += __shfl_xor(acc0, 32, 64);
    acc1 += __shfl_xor(acc1, 32, 64);
    acc2 += __shfl_xor(acc2, 32, 64);
    acc3 += __shfl_xor(acc3, 32, 64);
    const float bv  = bias[sub];
    const float o01 = (half ? acc1 : acc0) + bv;   // point i0+half
    const float o23 = (half ? acc3 : acc2) + bv;   // point i0+2+half
    Yp[(size_t)(i0 + half) * 32 + sub]     = (_Float16)o01;
    Yp[(size_t)(i0 + 2 + half) * 32 + sub] = (_Float16)o23;

    // fused BN stats into NREP slabs (32 atomics x2 per block over 64 slabs)
    __shared__ float sd[256];
    const int tid = threadIdx.x;
    float* __restrict__ slab = slab0 + (size_t)(blockIdx.x & (NREP - 1)) * 64;
    sd[tid] = o01 + o23;
    __syncthreads();
    if (tid < 32) {
        float t = 0.f;
#pragma unroll
        for (int k = 0; k < 8; ++k) t += sd[tid + 32 * k];
        atomicAdd(slab + tid, t);
    }
    __syncthreads();
    sd[tid] = o01 * o01 + o23 * o23;
    __syncthreads();
    if (tid < 32) {
        float t = 0.f;
#pragma unroll
        for (int k = 0; k < 8; ++k) t += sd[tid + 32 * k];
        atomicAdd(slab + 32 + tid, t);
    }
}

// ------ strided down conv: LDS grid rows, branched 4-chain, fp16 dot2 -------
__global__ __launch_bounds__(256) void k_down(const unsigned* __restrict__ X16,
                                              const int* __restrict__ grid,
                                              const uint4* __restrict__ Wh3,
                                              const float* __restrict__ bias,
                                              _Float16* __restrict__ Yh,
                                              unsigned char* __restrict__ mask,
                                              float* __restrict__ slab0,
                                              int* __restrict__ nacts) {
    const int b    = blockIdx.x;
    const int swz  = (b & 7) * (NB_DOWN / 8) + (b >> 3);
    const int tid  = threadIdx.x;
    const int wv   = tid >> 6;
    const int lane = tid & 63;
    const int sub  = lane & 31;
    const int half = lane >> 5;

    const int vox0 = swz * 64;
    const int ox0  = vox0 & 127;      // 0 or 64
    int t = vox0 >> 7;
    const int oy = t & 127; t >>= 7;
    const int oz = t & 15;
    const int bb = t >> 4;

    __shared__ int   gl[9][132];
    __shared__ float sd[256];
    __shared__ int   scnt[4];

    const int gx0 = 2 * ox0 - 1;
    for (int e = tid; e < 9 * 132; e += 256) {
        const int r  = e / 132, xo = e % 132;
        const int z  = 2 * oz - 1 + r / 3;
        const int y  = 2 * oy - 1 + r % 3;
        const int x  = gx0 + xo;
        int v = -1;
        if ((unsigned)z < (unsigned)D_ && (unsigned)y < (unsigned)H_ &&
            (unsigned)x < (unsigned)W_ && xo < 129)
            v = grid[((bb * D_ + z) * H_ + y) * W_ + x];
        gl[r][xo] = v;
    }
    __syncthreads();

    const int dz = sub / 9, dy = (sub / 3) % 3, dx = sub % 3;
    const int row = (sub < 27) ? dz * 3 + dy : 0;

    const float bv = bias[lane];
    float s = 0.f, s2 = 0.f;
    int cnt = 0;

    auto tap = [&](int ki, int ni, float& acc) {
        const uint4* __restrict__ fS = (const uint4*)(X16 + (size_t)ni * 16);
        const uint4* __restrict__ wb = Wh3 + (size_t)ki * 256 + lane;
#pragma unroll
        for (int q = 0; q < 4; ++q) {
            const uint4 fu = fS[q];
            const uint4 wu = wb[q * 64];
            acc = dot2(fu.x, wu.x, acc);
            acc = dot2(fu.y, wu.y, acc);
            acc = dot2(fu.z, wu.z, acc);
            acc = dot2(fu.w, wu.w, acc);
        }
    };

    for (int it = 0; it < 4; ++it) {
        const int v0 = wv * 16 + it * 4;   // 4 voxels this iteration
        const int n01 = (sub < 27) ? gl[row][2 * (v0 + half) + dx] : -1;
        const int n23 = (sub < 27) ? gl[row][2 * (v0 + 2 + half) + dx] : -1;
        const unsigned long long a01 = __ballot(n01 >= 0);
        const unsigned long long a23 = __ballot(n23 >= 0);
        unsigned m0 = (unsigned)a01 & 0x7FFFFFFu;
        unsigned m1 = (unsigned)(a01 >> 32) & 0x7FFFFFFu;
        unsigned m2 = (unsigned)a23 & 0x7FFFFFFu;
        unsigned m3 = (unsigned)(a23 >> 32) & 0x7FFFFFFu;
        const int mk0 = m0 ? 1 : 0, mk1 = m1 ? 1 : 0;
        const int mk2 = m2 ? 1 : 0, mk3 = m3 ? 1 : 0;

        float ac0 = 0.f, ac1 = 0.f, ac2 = 0.f, ac3 = 0.f;
        while (m0 | m1 | m2 | m3) {
            if (m0) { const int ki = __builtin_ctz(m0); m0 &= m0 - 1;
                      tap(ki, __builtin_amdgcn_readfirstlane(__shfl(n01, ki, 64)),      ac0); }
            if (m1) { const int ki = __builtin_ctz(m1); m1 &= m1 - 1;
                      tap(ki, __builtin_amdgcn_readfirstlane(__shfl(n01, ki + 32, 64)), ac1); }
            if (m2) { const int ki = __builtin_ctz(m2); m2 &= m2 - 1;
                      tap(ki, __builtin_amdgcn_readfirstlane(__shfl(n23, ki, 64)),      ac2); }
            if (m3) { const int ki = __builtin_ctz(m3); m3 &= m3 - 1;
                      tap(ki, __builtin_amdgcn_readfirstlane(__shfl(n23, ki + 32, 64)), ac3); }
        }

        const int vg = vox0 + v0;
        const float o0 = mk0 ? ac0 + bv : 0.f;
        const float o1 = mk1 ? ac1 + bv : 0.f;
        const float o2 = mk2 ? ac2 + bv : 0.f;
        const float o3 = mk3 ? ac3 + bv : 0.f;
        Yh[(size_t)vg * COUT + lane]       = (_Float16)o0;
        Yh[(size_t)(vg + 1) * COUT + lane] = (_Float16)o1;
        Yh[(size_t)(vg + 2) * COUT + lane] = (_Float16)o2;
        Yh[(size_t)(vg + 3) * COUT + lane] = (_Float16)o3;
        if (lane == 0) {
            mask[vg]     = (unsigned char)mk0;
            mask[vg + 1] = (unsigned char)mk1;
            mask[vg + 2] = (unsigned char)mk2;
            mask[vg + 3] = (unsigned char)mk3;
            cnt += mk0 + mk1 + mk2 + mk3;
        }
        s  += o0 + o1 + o2 + o3;
        s2 += o0 * o0 + o1 * o1 + o2 * o2 + o3 * o3;
    }

    float* __restrict__ slab = slab0 + (size_t)(b & (NREP - 1)) * 128;
    sd[tid] = s;
    if (lane == 0) scnt[wv] = cnt;
    __syncthreads();
    if (tid < 64) atomicAdd(slab + tid, sd[tid] + sd[tid + 64] + sd[tid + 128] + sd[tid + 192]);
    __syncthreads();
    sd[tid] = s2;
    __syncthreads();
    if (tid < 64) atomicAdd(slab + 64 + tid, sd[tid] + sd[tid + 64] + sd[tid + 128] + sd[tid + 192]);
    if (tid == 0) atomicAdd(nacts + (b & (NREP - 1)), scnt[0] + scnt[1] + scnt[2] + scnt[3]);
}

// ---------------- finalize scale/shift from NREP slabs (stages 1,2) ---------
template <int C>
__global__ void k_finslab(const float* __restrict__ slab0,
                          const float* __restrict__ g,
                          const float* __restrict__ be,
                          float n, float* __restrict__ ss) {
    const int c = threadIdx.x;
    if (c >= C) return;
    float sm = 0.f, s2 = 0.f;
    for (int r = 0; r < NREP; ++r) {
        sm += slab0[r * 2 * C + c];
        s2 += slab0[r * 2 * C + C + c];
    }
    const float m  = sm / n;
    const float v  = s2 / n - m * m;
    const float sc = g[c] * rsqrtf(v + EPSf);
    ss[c]     = sc;
    ss[C + c] = be[c] - m * sc;
}

// ---------------- finalize scale/shift (stage 3, folds NREP replicas) -------
__global__ void k_finstats3(const float* __restrict__ slab0,
                            const int* __restrict__ nacts,
                            const float* __restrict__ g,
                            const float* __restrict__ be,
                            float* __restrict__ ss) {
    const int c = threadIdx.x;   // 64 threads
    if (c >= 64) return;
    float sm = 0.f, s2 = 0.f;
    int na = 0;
    for (int r = 0; r < NREP; ++r) {
        sm += slab0[r * 128 + c];
        s2 += slab0[r * 128 + 64 + c];
        na += nacts[r];
    }
    const float n  = (float)(na > 0 ? na : 1);
    const float m  = sm / n;
    const float v  = s2 / n - m * m;
    const float sc = g[c] * rsqrtf(v + EPSf);
    ss[c]      = sc;
    ss[64 + c] = be[c] - m * sc;
}

// --------- normalize (BN+ReLU): fp16 pre-norm in -> packed fp16 out ---------
template <int C>
__global__ __launch_bounds__(256) void k_norm16(const unsigned* __restrict__ Yp2,
                                                const float* __restrict__ ss,
                                                unsigned* __restrict__ Xo16, long n4) {
    const long t = (long)blockIdx.x * 256 + threadIdx.x;
    if (t >= n4) return;
    const uint2 y = ((const uint2*)Yp2)[t];
    const h2 lo = as_h2(y.x), hi = as_h2(y.y);
    const int ch = (int)((t * 4) % C);
    float ox = fmaxf(fmaf((float)lo.x, ss[ch],     ss[C + ch]),     0.f);
    float oy = fmaxf(fmaf((float)lo.y, ss[ch + 1], ss[C + ch + 1]), 0.f);
    float oz = fmaxf(fmaf((float)hi.x, ss[ch + 2], ss[C + ch + 2]), 0.f);
    float ow = fmaxf(fmaf((float)hi.y, ss[ch + 3], ss[C + ch + 3]), 0.f);
    uint2 o; o.x = hpk(ox, oy); o.y = hpk(oz, ow);
    ((uint2*)Xo16)[t] = o;
}

// ---------------- stage-3 normalize: fp16 in, fp32 out ----------------
__global__ __launch_bounds__(256) void k_norm3(const _Float16* __restrict__ Yh,
                                               const unsigned char* __restrict__ mask,
                                               const float* __restrict__ ss,
                                               float* __restrict__ out) {
    const long n4 = (long)M_ * COUT / 4;
    const long t = (long)blockIdx.x * 256 + threadIdx.x;
    if (t >= n4) return;
    const long vox = t >> 4;
    const int ch = (int)((t * 4) & 63);
    float4 o;
    if (mask[vox]) {
        const uint2 yu = *(const uint2*)(Yh + t * 4);
        const h2 ylo = as_h2(yu.x), yhi = as_h2(yu.y);
        o.x = fmaxf(fmaf((float)ylo.x, ss[ch],     ss[64 + ch]),     0.f);
        o.y = fmaxf(fmaf((float)ylo.y, ss[ch + 1], ss[64 + ch + 1]), 0.f);
        o.z = fmaxf(fmaf((float)yhi.x, ss[ch + 2], ss[64 + ch + 2]), 0.f);
        o.w = fmaxf(fmaf((float)yhi.y, ss[ch + 3], ss[64 + ch + 3]), 0.f);
    } else {
        o.x = o.y = o.z = o.w = 0.f;
    }
    ((float4*)out)[t] = o;
}

extern "C" void kernel_launch(void* const* d_in, const int* in_sizes, int n_in,
                              void* d_out, int out_size, void* d_ws, size_t ws_size,
                              hipStream_t stream) {
    const float* feats = (const float*)d_in[0];
    const int*   coords = (const int*)d_in[1];
    const float* W1 = (const float*)d_in[2];
    const float* b1 = (const float*)d_in[3];
    const float* g1 = (const float*)d_in[4];
    const float* be1 = (const float*)d_in[5];
    const float* W2 = (const float*)d_in[6];
    const float* b2 = (const float*)d_in[7];
    const float* g2 = (const float*)d_in[8];
    const float* be2 = (const float*)d_in[9];
    const float* W3 = (const float*)d_in[10];
    const float* b3 = (const float*)d_in[11];
    const float* g3 = (const float*)d_in[12];
    const float* be3 = (const float*)d_in[13];
    float* out = (float*)d_out;

    char* ws = (char*)d_ws;
    const size_t gridBytes = (size_t)B_ * D_ * H_ * W_ * 4;   // 16,777,216
    const size_t f16Bytes  = (size_t)N_ * CIN * 2;            //  4,800,000
    const size_t bufPBytes = (size_t)N_ * CMID * 2;           //  9,600,000
    const size_t YhBytes   = (size_t)M_ * COUT * 2;           // 67,108,864
    int*       grid   = (int*)ws;
    unsigned*  feat16 = (unsigned*)(ws + gridBytes);
    _Float16*  bufP   = (_Float16*)(ws + gridBytes + f16Bytes);           // pre-norm
    unsigned*  bufH   = (unsigned*)(ws + gridBytes + f16Bytes + bufPBytes); // normalized
    _Float16*  Yh     = (_Float16*)(ws + gridBytes + f16Bytes + 2 * bufPBytes);
    unsigned char* mask = (unsigned char*)(ws + gridBytes + f16Bytes + 2 * bufPBytes + YhBytes);
    float* stats = (float*)(ws + gridBytes + f16Bytes + 2 * bufPBytes + YhBytes + (size_t)M_);

    float* ss1   = stats;                 // 64
    float* ss2   = stats + 64;            // 64
    float* ss3   = stats + 128;           // 128
    float* slab1 = stats + 1024;                        // NREP*64
    float* slab2 = stats + 1024 + NREP * 64;            // NREP*64
    float* slab3 = stats + 1024 + NREP * 128;           // NREP*128
    int*   nacts = (int*)(stats + 1024 + NREP * 256);   // NREP ints
    uint4* Wh1 = (uint4*)(stats + 32768);               // 1728 uint4
    uint4* Wh2 = Wh1 + 1728;                            // 3456 uint4
    uint4* Wh3 = Wh2 + 3456;                            // 6912 uint4

    hipMemsetAsync(grid, 0xFF, gridBytes, stream);
    hipMemsetAsync(stats + 1024, 0, (NREP * 256 + NREP) * 4, stream); // slabs+nacts

    k_scatter<<<(N_ + 255) / 256, 256, 0, stream>>>(coords, grid);
    k_twisth<<<(12096 + 255) / 256, 256, 0, stream>>>(W1, W2, W3, Wh1, Wh2, Wh3);
    k_feat16<<<(N_ * CIN / 4 + 255) / 256, 256, 0, stream>>>(feats, feat16);

    const int nb_subm = N_ / 16;   // 9375 blocks: 4 waves x 4 points, exact
    k_subm<CIN><<<nb_subm, 256, 0, stream>>>(feat16, coords, grid, Wh1, b1, bufP, slab1);
    k_finslab<CMID><<<1, 64, 0, stream>>>(slab1, g1, be1, (float)N_, ss1);
    k_norm16<CMID><<<(N_ * CMID / 4 + 255) / 256, 256, 0, stream>>>(
        (const unsigned*)bufP, ss1, bufH, (long)N_ * CMID / 4);

    k_subm<CMID><<<nb_subm, 256, 0, stream>>>(bufH, coords, grid, Wh2, b2, bufP, slab2);
    k_finslab<CMID><<<1, 64, 0, stream>>>(slab2, g2, be2, (float)N_, ss2);
    k_norm16<CMID><<<(N_ * CMID / 4 + 255) / 256, 256, 0, stream>>>(
        (const unsigned*)bufP, ss2, bufH, (long)N_ * CMID / 4);

    k_down<<<NB_DOWN, 256, 0, stream>>>(bufH, grid, Wh3, b3, Yh, mask, slab3, nacts);
    k_finstats3<<<1, 64, 0, stream>>>(slab3, nacts, g3, be3, ss3);
    k_norm3<<<(M_ * COUT / 4) / 256, 256, 0, stream>>>(Yh, mask, ss3, out);
}